// Round 8
// baseline (798.604 us; speedup 1.0000x reference)
//
#include <hip/hip_runtime.h>
#include <hip/hip_bf16.h>

// Problem constants: B=4, S=2048, D=1024, H=16, HD=64
#define S_LEN  2048
#define DMODEL 1024
#define NHEAD  16
#define HDIM   64
#define BSZ    4

// exp2-domain softmax constants
#define C_SCORE  0.18033688f        // 0.125 * log2(e)
#define C_MASK  -1.4426950e9f       // -1e9 * log2(e)

typedef __bf16 bf16_t;
typedef __bf16 bf16x8 __attribute__((ext_vector_type(8)));
typedef __bf16 bf16x4 __attribute__((ext_vector_type(4)));
typedef float  f32x4  __attribute__((ext_vector_type(4)));

typedef __attribute__((address_space(1))) void as1_void;
typedef __attribute__((address_space(3))) void as3_void;

__device__ __forceinline__ f32x4 mfma16(bf16x8 a, bf16x8 b, f32x4 c) {
    return __builtin_amdgcn_mfma_f32_16x16x32_bf16(a, b, c, 0, 0, 0);
}

__device__ __forceinline__ void fence_barrier() {
    // raw barrier: no compiler-forced vmcnt(0) drain (stores stay in flight).
    asm volatile("s_waitcnt lgkmcnt(0)" ::: "memory");
    __builtin_amdgcn_s_barrier();
}

// ---------------------------------------------------------------------------
__global__ __launch_bounds__(256) void cvt_x_kernel(const float* __restrict__ x,
                                                    bf16_t* __restrict__ xb, int n4) {
    int i = blockIdx.x * 256 + threadIdx.x;
    int stride = gridDim.x * 256;
    for (; i < n4; i += stride) {
        float4 v = ((const float4*)x)[i];
        bf16x4 t = { (bf16_t)v.x, (bf16_t)v.y, (bf16_t)v.z, (bf16_t)v.w };
        ((bf16x4*)xb)[i] = t;
    }
}

__global__ __launch_bounds__(256) void cvt_wT_kernel(const float* __restrict__ w,
                                                     bf16_t* __restrict__ wT) {
    __shared__ bf16_t t[64][65];
    const int bx = blockIdx.x * 64;
    const int by = blockIdx.y * 64;
    const int tx = threadIdx.x & 63, ty = threadIdx.x >> 6;
    #pragma unroll
    for (int rr = 0; rr < 64; rr += 4)
        t[tx][rr + ty] = (bf16_t)w[(size_t)(bx + rr + ty) * DMODEL + by + tx];
    __syncthreads();
    #pragma unroll
    for (int rr = 0; rr < 64; rr += 4)
        wT[(size_t)(by + rr + ty) * DMODEL + bx + tx] = t[rr + ty][tx];
}

__global__ __launch_bounds__(256) void transpose_v(const bf16_t* __restrict__ V,
                                                   bf16_t* __restrict__ Vt) {
    __shared__ __attribute__((aligned(16))) bf16_t t[64][72];
    const int bh = blockIdx.y;
    const int s0 = blockIdx.x * 64;
    const int tid = threadIdx.x;
    const bf16_t* Vb = V + (size_t)bh * S_LEN * HDIM;
    bf16_t* Vo = Vt + (size_t)bh * HDIM * S_LEN;
    #pragma unroll
    for (int p = 0; p < 2; ++p) {
        const int sl = p * 32 + (tid >> 3);
        const int c8 = (tid & 7) * 8;
        bf16x8 v = *(const bf16x8*)(Vb + (size_t)(s0 + sl) * HDIM + c8);
        #pragma unroll
        for (int j = 0; j < 8; ++j) t[c8 + j][sl] = v[j];
    }
    __syncthreads();
    #pragma unroll
    for (int p = 0; p < 2; ++p) {
        const int dl = p * 32 + (tid >> 3);
        const int s8 = (tid & 7) * 8;
        bf16x8 v = *(const bf16x8*)(&t[dl][s8]);
        *(bf16x8*)(Vo + (size_t)dl * S_LEN + s0 + s8) = v;
    }
}

// ---------------------------------------------------------------------------
// GEMM: C = A(Mx1024) * Bt(Nx1024)^T + bias. 128x128 tile, 4 waves (2x2).
template <int MODE>
__global__ __launch_bounds__(256) void gemm_bt(const bf16_t* __restrict__ A,
                                               const bf16_t* __restrict__ Bt,
                                               const float* __restrict__ b0,
                                               const float* __restrict__ b1,
                                               const float* __restrict__ b2,
                                               bf16_t* __restrict__ o0,
                                               bf16_t* __restrict__ o1,
                                               bf16_t* __restrict__ o2,
                                               float* __restrict__ of) {
    constexpr int GK = 1024;
    __shared__ __attribute__((aligned(16))) bf16_t As[128 * 32];
    __shared__ __attribute__((aligned(16))) bf16_t Bs[128 * 32];

    const int tid  = threadIdx.x;
    const int wave = tid >> 6, lane = tid & 63;
    const int col16 = lane & 15, g = lane >> 4;
    const int wr = wave >> 1, wc = wave & 1;
    const int bn0 = blockIdx.x * 128, bm0 = blockIdx.y * 128;

    const int r4 = tid >> 2;
    const int c8 = (tid & 3) * 8;

    f32x4 acc[4][4] = {};

    for (int k0 = 0; k0 < GK; k0 += 32) {
        __syncthreads();
        #pragma unroll
        for (int i = 0; i < 2; ++i) {
            __builtin_amdgcn_global_load_lds(
                (const as1_void*)(A + (size_t)(bm0 + i * 64 + r4) * GK + k0 + c8),
                (as3_void*)(As + (i * 64 + wave * 16) * 32), 16, 0, 0);
            __builtin_amdgcn_global_load_lds(
                (const as1_void*)(Bt + (size_t)(bn0 + i * 64 + r4) * GK + k0 + c8),
                (as3_void*)(Bs + (i * 64 + wave * 16) * 32), 16, 0, 0);
        }
        __syncthreads();

        bf16x8 af[4], bfr[4];
        #pragma unroll
        for (int i = 0; i < 4; ++i) {
            af[i]  = *(const bf16x8*)(As + (wr * 64 + i * 16 + col16) * 32 + g * 8);
            bfr[i] = *(const bf16x8*)(Bs + (wc * 64 + i * 16 + col16) * 32 + g * 8);
        }
        #pragma unroll
        for (int mi = 0; mi < 4; ++mi)
            #pragma unroll
            for (int ni = 0; ni < 4; ++ni)
                acc[mi][ni] = mfma16(af[mi], bfr[ni], acc[mi][ni]);
    }

    #pragma unroll
    for (int ni = 0; ni < 4; ++ni) {
        const int gn = bn0 + wc * 64 + ni * 16 + col16;
        if (MODE == 0) {
            const int proj = bn0 >> 10;
            const float* bias = proj == 0 ? b0 : (proj == 1 ? b1 : b2);
            bf16_t* outp      = proj == 0 ? o0 : (proj == 1 ? o1 : o2);
            const int n1 = gn & 1023, h = n1 >> 6, hd = n1 & 63;
            const float bv = bias[n1];
            #pragma unroll
            for (int mi = 0; mi < 4; ++mi)
                #pragma unroll
                for (int r = 0; r < 4; ++r) {
                    const int gm = bm0 + wr * 64 + mi * 16 + g * 4 + r;
                    const int b = gm >> 11, s = gm & 2047;
                    outp[(((size_t)b * NHEAD + h) * S_LEN + s) * HDIM + hd] =
                        (bf16_t)(acc[mi][ni][r] + bv);
                }
        } else {
            const float bv = b0[gn];
            #pragma unroll
            for (int mi = 0; mi < 4; ++mi)
                #pragma unroll
                for (int r = 0; r < 4; ++r) {
                    const int gm = bm0 + wr * 64 + mi * 16 + g * 4 + r;
                    of[(size_t)gm * DMODEL + gn] = acc[mi][ni][r] + bv;
                }
        }
    }
}

// ---------------------------------------------------------------------------
// Fused attention v8: producer/consumer wave specialization.
// 512 thr = 8 waves; block owns 128 q-rows of one head; 1 block/CU (LDS 93KB).
// Sweep 1: all 8 waves, 16 rows each, l-only (no stores) -> crow via LDS.
// Sweep 2: waves 0-3 produce (QK^T -> exp2 -> P fp32 into LDS dbuf + bf16 Pt
//          -> PV MFMA; NO global stores, so their vmcnt waits are pure counted
//          load waits). Waves 4-7 write (ds_read P -> nt-store attnW; their
//          store queue is never drained by a load wait). Raw s_barrier +
//          lgkmcnt(0) only -> no compiler vmcnt(0) drain at barriers; stores
//          stay in flight across iterations -> HBM write pipe stays saturated.
// Buffer protocol: producer fills Pl[it&1] in (B[it-1],B[it]); writer drains
// Pl[(it-1)&1] in the same interval; rewrite of a buffer is 2 barriers later.
__global__ __launch_bounds__(512, 2) void attn_ws(const bf16_t* __restrict__ Q,
                                                  const bf16_t* __restrict__ K,
                                                  const bf16_t* __restrict__ Vt,
                                                  const float* __restrict__ mask,
                                                  float* __restrict__ attnW,
                                                  bf16_t* __restrict__ ctx) {
    __shared__ __attribute__((aligned(16))) float  Pl[2][128][72];  // 73.7 KB
    __shared__ __attribute__((aligned(16))) bf16_t Pt[4][32][72];   // 18.4 KB
    __shared__ float crow_lds[128];

    const int tid = threadIdx.x, wave = tid >> 6, lane = tid & 63;
    const int col16 = lane & 15, g = lane >> 4;

    // bijective XCD swizzle (1024 blocks): 16 blocks of a head share one XCD L2
    const int lin = blockIdx.x;
    const int logical = (lin & 7) * 128 + (lin >> 3);
    const int bh = logical >> 4, qt = logical & 15;
    const int b = bh >> 4, h = bh & 15;
    const int q0b = qt * 128;

    const bf16_t* Qb = Q + (size_t)bh * S_LEN * HDIM;
    const bf16_t* Kb = K + (size_t)bh * S_LEN * HDIM;
    const bf16_t* Vb = Vt + (size_t)bh * HDIM * S_LEN;
    const float* mp = mask + (size_t)b * S_LEN;

    bf16x8 kbA[8], kbB[8];
    auto loadK = [&](bf16x8 (&dst)[8], int it) {
        const int kk0 = it << 6;
        #pragma unroll
        for (int nj = 0; nj < 4; ++nj) {
            const bf16_t* kp = Kb + (size_t)(kk0 + nj * 16 + col16) * HDIM + g * 8;
            dst[nj * 2]     = *(const bf16x8*)(kp);
            dst[nj * 2 + 1] = *(const bf16x8*)(kp + 32);
        }
    };

    // ---- sweep 1: all 8 waves, 16 rows each, l-only ----
    {
        const int q1 = q0b + wave * 16;
        bf16x8 qa1[2];
        qa1[0] = *(const bf16x8*)(Qb + (size_t)(q1 + col16) * HDIM + g * 8);
        qa1[1] = *(const bf16x8*)(Qb + (size_t)(q1 + col16) * HDIM + 32 + g * 8);

        f32x4 lacc = {0.f, 0.f, 0.f, 0.f};
        auto body1 = [&](bf16x8 (&kc)[8], bf16x8 (&kn)[8], int it) {
            const int kk0 = it << 6;
            if (it < 31) loadK(kn, it + 1);
            f32x4 mvr[4];
            #pragma unroll
            for (int nj = 0; nj < 4; ++nj) mvr[nj] = ((const f32x4*)(mp + kk0 + nj * 16))[g];
            #pragma unroll
            for (int nj = 0; nj < 4; ++nj) {
                f32x4 t0 = {0.f, 0.f, 0.f, 0.f};
                t0 = mfma16(kc[nj * 2], qa1[0], t0);
                t0 = mfma16(kc[nj * 2 + 1], qa1[1], t0);
                #pragma unroll
                for (int r = 0; r < 4; ++r)
                    lacc[r] += exp2f(fmaf(t0[r], C_SCORE, mvr[nj][r] * C_MASK));
            }
        };
        loadK(kbA, 0);
        for (int it = 0; it < 32; it += 2) {
            body1(kbA, kbB, it);
            body1(kbB, kbA, it + 1);
        }
        float lr = (lacc[0] + lacc[1]) + (lacc[2] + lacc[3]);
        lr += __shfl_xor(lr, 16);
        lr += __shfl_xor(lr, 32);
        if (lane < 16) crow_lds[wave * 16 + col16] = -__log2f(lr);
    }
    __syncthreads();

    // ---- sweep 2: specialized roles ----
    if (wave < 4) {
        // PRODUCER: 32 q-rows, no global stores.
        const int p = wave;
        const int q2 = q0b + p * 32;
        bf16x8 qa2[2][2];
        #pragma unroll
        for (int hh = 0; hh < 2; ++hh)
            #pragma unroll
            for (int kh = 0; kh < 2; ++kh)
                qa2[hh][kh] = *(const bf16x8*)(Qb + (size_t)(q2 + hh * 16 + col16) * HDIM +
                                               kh * 32 + g * 8);
        const float crow0 = crow_lds[p * 32 + col16];
        const float crow1 = crow_lds[p * 32 + 16 + col16];

        f32x4 o[2][4] = {};

        auto bodyP = [&](bf16x8 (&kc)[8], bf16x8 (&kn)[8], int it) {
            const int kk0 = it << 6;
            const int cur = it & 1;
            // V first (older), K prefetch after: waiting for V never waits K(it+1).
            bf16x8 vb[8];
            #pragma unroll
            for (int nd = 0; nd < 4; ++nd) {
                const bf16_t* vp = Vb + (size_t)(nd * 16 + col16) * S_LEN + kk0 + g * 8;
                vb[nd * 2]     = *(const bf16x8*)(vp);
                vb[nd * 2 + 1] = *(const bf16x8*)(vp + 32);
            }
            if (it < 31) loadK(kn, it + 1);
            f32x4 mvr[4];
            #pragma unroll
            for (int nj = 0; nj < 4; ++nj) mvr[nj] = ((const f32x4*)(mp + kk0 + nj * 16))[g];

            #pragma unroll
            for (int nj = 0; nj < 4; ++nj) {
                f32x4 t0 = {0.f, 0.f, 0.f, 0.f}, t1 = {0.f, 0.f, 0.f, 0.f};
                __builtin_amdgcn_s_setprio(1);
                t0 = mfma16(kc[nj * 2], qa2[0][0], t0);
                t0 = mfma16(kc[nj * 2 + 1], qa2[0][1], t0);
                t1 = mfma16(kc[nj * 2], qa2[1][0], t1);
                t1 = mfma16(kc[nj * 2 + 1], qa2[1][1], t1);
                __builtin_amdgcn_s_setprio(0);
                f32x4 pn0, pn1;
                bf16x4 pb0, pb1;
                #pragma unroll
                for (int r = 0; r < 4; ++r) {
                    const float mm = mvr[nj][r] * C_MASK;
                    pn0[r] = exp2f(fmaf(t0[r], C_SCORE, mm + crow0));
                    pn1[r] = exp2f(fmaf(t1[r], C_SCORE, mm + crow1));
                    pb0[r] = (bf16_t)pn0[r];
                    pb1[r] = (bf16_t)pn1[r];
                }
                *(f32x4*)(&Pl[cur][p * 32 + col16][nj * 16 + g * 4]) = pn0;
                *(f32x4*)(&Pl[cur][p * 32 + 16 + col16][nj * 16 + g * 4]) = pn1;
                *(bf16x4*)(&Pt[p][col16][nj * 16 + g * 4]) = pb0;
                *(bf16x4*)(&Pt[p][16 + col16][nj * 16 + g * 4]) = pb1;
            }

            __builtin_amdgcn_s_setprio(1);
            #pragma unroll
            for (int hh = 0; hh < 2; ++hh)
                #pragma unroll
                for (int kh = 0; kh < 2; ++kh) {
                    const bf16x8 pa = *(const bf16x8*)(&Pt[p][hh * 16 + col16][kh * 32 + g * 8]);
                    #pragma unroll
                    for (int nd = 0; nd < 4; ++nd)
                        o[hh][nd] = mfma16(vb[nd * 2 + kh], pa, o[hh][nd]);
                }
            __builtin_amdgcn_s_setprio(0);
            fence_barrier();
        };

        loadK(kbA, 0);
        for (int it = 0; it < 32; it += 2) {
            bodyP(kbA, kbB, it);
            bodyP(kbB, kbA, it + 1);
        }

        // ctx (B,S,D) bf16
        #pragma unroll
        for (int hh = 0; hh < 2; ++hh) {
            bf16_t* cp = ctx + ((size_t)b * S_LEN + q2 + hh * 16 + col16) * DMODEL + h * HDIM;
            #pragma unroll
            for (int nd = 0; nd < 4; ++nd) {
                bf16x4 cv;
                #pragma unroll
                for (int r = 0; r < 4; ++r) cv[r] = (bf16_t)o[hh][nd][r];
                *(bf16x4*)(cp + nd * 16 + g * 4) = cv;
            }
        }
    } else {
        // WRITER: pure LDS->global nt-store stream; only register-reuse waits.
        const int wi = wave - 4;
        float* aw0 = attnW + (size_t)(bh * S_LEN + q0b + wi * 32 + col16) * S_LEN;
        float* aw1 = attnW + (size_t)(bh * S_LEN + q0b + wi * 32 + 16 + col16) * S_LEN;

        for (int it = 0; it < 32; ++it) {
            if (it > 0) {
                const int pb = (it - 1) & 1;
                const int kk0 = (it - 1) << 6;
                #pragma unroll
                for (int nj = 0; nj < 4; ++nj) {
                    f32x4 v0 = *(const f32x4*)(&Pl[pb][wi * 32 + col16][nj * 16 + g * 4]);
                    f32x4 v1 = *(const f32x4*)(&Pl[pb][wi * 32 + 16 + col16][nj * 16 + g * 4]);
                    __builtin_nontemporal_store(v0, (f32x4*)(aw0 + kk0 + nj * 16 + g * 4));
                    __builtin_nontemporal_store(v1, (f32x4*)(aw1 + kk0 + nj * 16 + g * 4));
                }
            }
            fence_barrier();
        }
        // final drain: buffer filled at it=31 (Pl[1])
        {
            const int kk0 = 31 << 6;
            #pragma unroll
            for (int nj = 0; nj < 4; ++nj) {
                f32x4 v0 = *(const f32x4*)(&Pl[1][wi * 32 + col16][nj * 16 + g * 4]);
                f32x4 v1 = *(const f32x4*)(&Pl[1][wi * 32 + 16 + col16][nj * 16 + g * 4]);
                __builtin_nontemporal_store(v0, (f32x4*)(aw0 + kk0 + nj * 16 + g * 4));
                __builtin_nontemporal_store(v1, (f32x4*)(aw1 + kk0 + nj * 16 + g * 4));
            }
        }
    }
}

// ---------------------------------------------------------------------------
extern "C" void kernel_launch(void* const* d_in, const int* in_sizes, int n_in,
                              void* d_out, int out_size, void* d_ws, size_t ws_size,
                              hipStream_t stream) {
    const float* x    = (const float*)d_in[0];
    const float* mask = (const float*)d_in[1];
    const float* wq   = (const float*)d_in[2];
    const float* bq   = (const float*)d_in[3];
    const float* wk   = (const float*)d_in[4];
    const float* bk   = (const float*)d_in[5];
    const float* wv   = (const float*)d_in[6];
    const float* bv   = (const float*)d_in[7];
    const float* wo   = (const float*)d_in[8];
    const float* bo   = (const float*)d_in[9];

    const size_t nX = (size_t)BSZ * S_LEN * DMODEL;      // 8388608
    const size_t nW = (size_t)DMODEL * DMODEL;           // 1048576

    char* ws = (char*)d_ws;
    size_t off = 0;
    bf16_t* xb     = (bf16_t*)(ws + off); off += nX * 2;
    bf16_t* wqkvT  = (bf16_t*)(ws + off); off += 3 * nW * 2;
    bf16_t* woT    = (bf16_t*)(ws + off); off += nW * 2;
    bf16_t* qbh    = (bf16_t*)(ws + off); off += nX * 2;
    bf16_t* kbh    = (bf16_t*)(ws + off); off += nX * 2;
    bf16_t* vrow   = (bf16_t*)(ws + off); off += nX * 2;
    bf16_t* vtb    = (bf16_t*)(ws + off); off += nX * 2;
    bf16_t* ctx    = (bf16_t*)(ws + off); off += nX * 2;
    if (ws_size < off) return;  // workspace too small: loud failure (output stays zero)

    float* outp  = (float*)d_out;
    float* attnW = outp + nX;  // out is B*S*D, then attn weights B*H*S*S

    cvt_x_kernel<<<4096, 256, 0, stream>>>(x, xb, (int)(nX / 4));
    cvt_wT_kernel<<<dim3(16, 16), 256, 0, stream>>>(wq, wqkvT);
    cvt_wT_kernel<<<dim3(16, 16), 256, 0, stream>>>(wk, wqkvT + nW);
    cvt_wT_kernel<<<dim3(16, 16), 256, 0, stream>>>(wv, wqkvT + 2 * nW);
    cvt_wT_kernel<<<dim3(16, 16), 256, 0, stream>>>(wo, woT);

    gemm_bt<0><<<dim3(24, 64), 256, 0, stream>>>(xb, wqkvT, bq, bk, bv,
                                                 qbh, kbh, vrow, nullptr);
    transpose_v<<<dim3(32, 64), 256, 0, stream>>>(vrow, vtb);

    attn_ws<<<1024, 512, 0, stream>>>(qbh, kbh, vtb, mask, attnW, ctx);

    gemm_bt<2><<<dim3(8, 64), 256, 0, stream>>>(ctx, woT, bo, nullptr, nullptr,
                                                nullptr, nullptr, nullptr, outp);
}

// Round 9
// 549.965 us; speedup vs baseline: 1.4521x; 1.4521x over previous
//
#include <hip/hip_runtime.h>
#include <hip/hip_bf16.h>

// Problem constants: B=4, S=2048, D=1024, H=16, HD=64
#define S_LEN  2048
#define DMODEL 1024
#define NHEAD  16
#define HDIM   64
#define BSZ    4

// exp2-domain softmax constants
#define C_SCORE  0.18033688f        // 0.125 * log2(e)
#define C_MASK  -1.4426950e9f       // -1e9 * log2(e)

typedef __bf16 bf16_t;
typedef __bf16 bf16x8 __attribute__((ext_vector_type(8)));
typedef __bf16 bf16x4 __attribute__((ext_vector_type(4)));
typedef float  f32x4  __attribute__((ext_vector_type(4)));

typedef __attribute__((address_space(1))) void as1_void;
typedef __attribute__((address_space(3))) void as3_void;

__device__ __forceinline__ f32x4 mfma16(bf16x8 a, bf16x8 b, f32x4 c) {
    return __builtin_amdgcn_mfma_f32_16x16x32_bf16(a, b, c, 0, 0, 0);
}

// ---------------------------------------------------------------------------
__global__ __launch_bounds__(256) void cvt_x_kernel(const float* __restrict__ x,
                                                    bf16_t* __restrict__ xb, int n4) {
    int i = blockIdx.x * 256 + threadIdx.x;
    int stride = gridDim.x * 256;
    for (; i < n4; i += stride) {
        float4 v = ((const float4*)x)[i];
        bf16x4 t = { (bf16_t)v.x, (bf16_t)v.y, (bf16_t)v.z, (bf16_t)v.w };
        ((bf16x4*)xb)[i] = t;
    }
}

__global__ __launch_bounds__(256) void cvt_wT_kernel(const float* __restrict__ w,
                                                     bf16_t* __restrict__ wT) {
    __shared__ bf16_t t[64][65];
    const int bx = blockIdx.x * 64;
    const int by = blockIdx.y * 64;
    const int tx = threadIdx.x & 63, ty = threadIdx.x >> 6;
    #pragma unroll
    for (int rr = 0; rr < 64; rr += 4)
        t[tx][rr + ty] = (bf16_t)w[(size_t)(bx + rr + ty) * DMODEL + by + tx];
    __syncthreads();
    #pragma unroll
    for (int rr = 0; rr < 64; rr += 4)
        wT[(size_t)(by + rr + ty) * DMODEL + bx + tx] = t[rr + ty][tx];
}

__global__ __launch_bounds__(256) void transpose_v(const bf16_t* __restrict__ V,
                                                   bf16_t* __restrict__ Vt) {
    __shared__ __attribute__((aligned(16))) bf16_t t[64][72];
    const int bh = blockIdx.y;
    const int s0 = blockIdx.x * 64;
    const int tid = threadIdx.x;
    const bf16_t* Vb = V + (size_t)bh * S_LEN * HDIM;
    bf16_t* Vo = Vt + (size_t)bh * HDIM * S_LEN;
    #pragma unroll
    for (int p = 0; p < 2; ++p) {
        const int sl = p * 32 + (tid >> 3);
        const int c8 = (tid & 7) * 8;
        bf16x8 v = *(const bf16x8*)(Vb + (size_t)(s0 + sl) * HDIM + c8);
        #pragma unroll
        for (int j = 0; j < 8; ++j) t[c8 + j][sl] = v[j];
    }
    __syncthreads();
    #pragma unroll
    for (int p = 0; p < 2; ++p) {
        const int dl = p * 32 + (tid >> 3);
        const int s8 = (tid & 7) * 8;
        bf16x8 v = *(const bf16x8*)(&t[dl][s8]);
        *(bf16x8*)(Vo + (size_t)dl * S_LEN + s0 + s8) = v;
    }
}

// ---------------------------------------------------------------------------
// GEMM: C = A(Mx1024) * Bt(Nx1024)^T + bias. 128x128 tile, 4 waves (2x2).
// MODE 0: fused QKV (N=3072): Q,K,V bf16 (B,H,S,HD) row-major.
// MODE 2: out-projection (N=1024): fp32 (B,S,D).
template <int MODE>
__global__ __launch_bounds__(256) void gemm_bt(const bf16_t* __restrict__ A,
                                               const bf16_t* __restrict__ Bt,
                                               const float* __restrict__ b0,
                                               const float* __restrict__ b1,
                                               const float* __restrict__ b2,
                                               bf16_t* __restrict__ o0,
                                               bf16_t* __restrict__ o1,
                                               bf16_t* __restrict__ o2,
                                               float* __restrict__ of) {
    constexpr int GK = 1024;
    __shared__ __attribute__((aligned(16))) bf16_t As[128 * 32];
    __shared__ __attribute__((aligned(16))) bf16_t Bs[128 * 32];

    const int tid  = threadIdx.x;
    const int wave = tid >> 6, lane = tid & 63;
    const int col16 = lane & 15, g = lane >> 4;
    const int wr = wave >> 1, wc = wave & 1;
    const int bn0 = blockIdx.x * 128, bm0 = blockIdx.y * 128;

    const int r4 = tid >> 2;
    const int c8 = (tid & 3) * 8;

    f32x4 acc[4][4] = {};

    for (int k0 = 0; k0 < GK; k0 += 32) {
        __syncthreads();
        #pragma unroll
        for (int i = 0; i < 2; ++i) {
            __builtin_amdgcn_global_load_lds(
                (const as1_void*)(A + (size_t)(bm0 + i * 64 + r4) * GK + k0 + c8),
                (as3_void*)(As + (i * 64 + wave * 16) * 32), 16, 0, 0);
            __builtin_amdgcn_global_load_lds(
                (const as1_void*)(Bt + (size_t)(bn0 + i * 64 + r4) * GK + k0 + c8),
                (as3_void*)(Bs + (i * 64 + wave * 16) * 32), 16, 0, 0);
        }
        __syncthreads();

        bf16x8 af[4], bfr[4];
        #pragma unroll
        for (int i = 0; i < 4; ++i) {
            af[i]  = *(const bf16x8*)(As + (wr * 64 + i * 16 + col16) * 32 + g * 8);
            bfr[i] = *(const bf16x8*)(Bs + (wc * 64 + i * 16 + col16) * 32 + g * 8);
        }
        #pragma unroll
        for (int mi = 0; mi < 4; ++mi)
            #pragma unroll
            for (int ni = 0; ni < 4; ++ni)
                acc[mi][ni] = mfma16(af[mi], bfr[ni], acc[mi][ni]);
    }

    #pragma unroll
    for (int ni = 0; ni < 4; ++ni) {
        const int gn = bn0 + wc * 64 + ni * 16 + col16;
        if (MODE == 0) {
            const int proj = bn0 >> 10;
            const float* bias = proj == 0 ? b0 : (proj == 1 ? b1 : b2);
            bf16_t* outp      = proj == 0 ? o0 : (proj == 1 ? o1 : o2);
            const int n1 = gn & 1023, h = n1 >> 6, hd = n1 & 63;
            const float bv = bias[n1];
            #pragma unroll
            for (int mi = 0; mi < 4; ++mi)
                #pragma unroll
                for (int r = 0; r < 4; ++r) {
                    const int gm = bm0 + wr * 64 + mi * 16 + g * 4 + r;
                    const int b = gm >> 11, s = gm & 2047;
                    outp[(((size_t)b * NHEAD + h) * S_LEN + s) * HDIM + hd] =
                        (bf16_t)(acc[mi][ni][r] + bv);
                }
        } else {
            const float bv = b0[gn];
            #pragma unroll
            for (int mi = 0; mi < 4; ++mi)
                #pragma unroll
                for (int r = 0; r < 4; ++r) {
                    const int gm = bm0 + wr * 64 + mi * 16 + g * 4 + r;
                    of[(size_t)gm * DMODEL + gn] = acc[mi][ni][r] + bv;
                }
        }
    }
}

// ---------------------------------------------------------------------------
// Fused attention v9: r6 structure + DEFERRED STORES (issue-order inversion).
// vmcnt retires in issue order, so a load issued after stores cannot be
// consumed until the stores retire. r3..r7 issued [stores(it)] before
// [loads(it+1)] -> every MFMA wait drained the store queue -> write pipe
// starved in bursts (~2.4 TB/s). Fix: keep P(it) fp32 in registers and issue
// its 8 nt-stores at the START of iteration it+1, AFTER that iteration's
// K/V loads. Consuming those loads then needs only vmcnt(8) (younger stores
// may stay outstanding); stores get a full iteration of compute to drain.
// sched_barrier(0) fences pin [loads][stores][compute] issue order.
__global__ __launch_bounds__(256, 2) void attn_fused(const bf16_t* __restrict__ Q,
                                                     const bf16_t* __restrict__ K,
                                                     const bf16_t* __restrict__ Vt,
                                                     const float* __restrict__ mask,
                                                     float* __restrict__ attnW,
                                                     bf16_t* __restrict__ ctx) {
    __shared__ __attribute__((aligned(16))) bf16_t Pt[4][32][72];
    const int tid = threadIdx.x, wave = tid >> 6, lane = tid & 63;
    const int col16 = lane & 15, g = lane >> 4;

    // bijective XCD swizzle (1024 blocks, 1024 % 8 == 0)
    const int lin = blockIdx.y * 16 + blockIdx.x;
    const int logical = (lin & 7) * 128 + (lin >> 3);
    const int bh = logical >> 4, qt = logical & 15;
    const int b = bh >> 4, h = bh & 15;
    const int q0 = qt * 128 + wave * 32;

    const bf16_t* Qb = Q + (size_t)bh * S_LEN * HDIM;
    const bf16_t* Kb = K + (size_t)bh * S_LEN * HDIM;
    const bf16_t* Vb = Vt + (size_t)bh * HDIM * S_LEN;
    const float* mp = mask + (size_t)b * S_LEN;

    // Q B-frags for both 16-row halves
    bf16x8 qa[2][2];
    #pragma unroll
    for (int hh = 0; hh < 2; ++hh)
        #pragma unroll
        for (int kh = 0; kh < 2; ++kh)
            qa[hh][kh] = *(const bf16x8*)(Qb + (size_t)(q0 + hh * 16 + col16) * HDIM +
                                          kh * 32 + g * 8);

    bf16x8 kbA[8], kbB[8];
    auto loadK = [&](bf16x8 (&dst)[8], int it) {
        const int kk0 = it << 6;
        #pragma unroll
        for (int nj = 0; nj < 4; ++nj) {
            const bf16_t* kp = Kb + (size_t)(kk0 + nj * 16 + col16) * HDIM + g * 8;
            dst[nj * 2]     = *(const bf16x8*)(kp);
            dst[nj * 2 + 1] = *(const bf16x8*)(kp + 32);
        }
    };

    // ---- sweep 1: l only, per-nj fused (no stores -> unchanged) ----
    f32x4 lacc[2] = {};

    auto body1 = [&](bf16x8 (&kc)[8], bf16x8 (&kn)[8], int it) {
        const int kk0 = it << 6;
        if (it < 31) loadK(kn, it + 1);
        f32x4 mvr[4];
        #pragma unroll
        for (int nj = 0; nj < 4; ++nj) mvr[nj] = ((const f32x4*)(mp + kk0 + nj * 16))[g];
        #pragma unroll
        for (int nj = 0; nj < 4; ++nj) {
            f32x4 t0 = {0.f, 0.f, 0.f, 0.f}, t1 = {0.f, 0.f, 0.f, 0.f};
            __builtin_amdgcn_s_setprio(1);
            t0 = mfma16(kc[nj * 2], qa[0][0], t0);
            t0 = mfma16(kc[nj * 2 + 1], qa[0][1], t0);
            t1 = mfma16(kc[nj * 2], qa[1][0], t1);
            t1 = mfma16(kc[nj * 2 + 1], qa[1][1], t1);
            __builtin_amdgcn_s_setprio(0);
            #pragma unroll
            for (int r = 0; r < 4; ++r) {
                const float mm = mvr[nj][r] * C_MASK;
                lacc[0][r] += exp2f(fmaf(t0[r], C_SCORE, mm));
                lacc[1][r] += exp2f(fmaf(t1[r], C_SCORE, mm));
            }
        }
    };

    loadK(kbA, 0);
    for (int it = 0; it < 32; it += 2) {
        body1(kbA, kbB, it);
        body1(kbB, kbA, it + 1);
    }

    float crow[2];
    #pragma unroll
    for (int hh = 0; hh < 2; ++hh) {
        float lr = (lacc[hh][0] + lacc[hh][1]) + (lacc[hh][2] + lacc[hh][3]);
        lr += __shfl_xor(lr, 16);
        lr += __shfl_xor(lr, 32);
        crow[hh] = -__log2f(lr);
    }

    // ---- sweep 2: loads -> deferred stores(prev) -> compute ----
    f32x4 o[2][4] = {};
    float* awp[2];
    #pragma unroll
    for (int hh = 0; hh < 2; ++hh)
        awp[hh] = attnW + (size_t)(bh * S_LEN + q0 + hh * 16 + col16) * S_LEN;

    f32x4 pnA[2][4], pnB[2][4];   // deferred P fp32 (named sets, 2x-unrolled swap)

    auto body2 = [&](bf16x8 (&kc)[8], bf16x8 (&kn)[8],
                     f32x4 (&pnSt)[2][4], f32x4 (&pnMk)[2][4], int it) {
        const int kk0 = it << 6;
        // --- step 1: ALL loads first (K prefetch + V current) ---
        if (it < 31) loadK(kn, it + 1);
        bf16x8 vb[8];
        #pragma unroll
        for (int nd = 0; nd < 4; ++nd) {
            const bf16_t* vp = Vb + (size_t)(nd * 16 + col16) * S_LEN + kk0 + g * 8;
            vb[nd * 2]     = *(const bf16x8*)(vp);
            vb[nd * 2 + 1] = *(const bf16x8*)(vp + 32);
        }
        f32x4 mvr[4];
        #pragma unroll
        for (int nj = 0; nj < 4; ++nj) mvr[nj] = ((const f32x4*)(mp + kk0 + nj * 16))[g];
        __builtin_amdgcn_sched_barrier(0);
        // --- step 2: deferred nt-stores from previous iteration ---
        if (it > 0) {
            const int kkp = kk0 - 64;
            #pragma unroll
            for (int hh = 0; hh < 2; ++hh)
                #pragma unroll
                for (int nj = 0; nj < 4; ++nj)
                    __builtin_nontemporal_store(pnSt[hh][nj],
                        (f32x4*)(awp[hh] + kkp + nj * 16 + g * 4));
        }
        __builtin_amdgcn_sched_barrier(0);
        // --- step 3: compute; load-consume waits tolerate outstanding stores ---
        #pragma unroll
        for (int nj = 0; nj < 4; ++nj) {
            f32x4 t0 = {0.f, 0.f, 0.f, 0.f}, t1 = {0.f, 0.f, 0.f, 0.f};
            __builtin_amdgcn_s_setprio(1);
            t0 = mfma16(kc[nj * 2], qa[0][0], t0);
            t0 = mfma16(kc[nj * 2 + 1], qa[0][1], t0);
            t1 = mfma16(kc[nj * 2], qa[1][0], t1);
            t1 = mfma16(kc[nj * 2 + 1], qa[1][1], t1);
            __builtin_amdgcn_s_setprio(0);
            bf16x4 pb0, pb1;
            #pragma unroll
            for (int r = 0; r < 4; ++r) {
                const float mm = mvr[nj][r] * C_MASK;
                pnMk[0][nj][r] = exp2f(fmaf(t0[r], C_SCORE, mm + crow[0]));
                pnMk[1][nj][r] = exp2f(fmaf(t1[r], C_SCORE, mm + crow[1]));
                pb0[r] = (bf16_t)pnMk[0][nj][r];
                pb1[r] = (bf16_t)pnMk[1][nj][r];
            }
            *(bf16x4*)(&Pt[wave][col16][nj * 16 + g * 4]) = pb0;
            *(bf16x4*)(&Pt[wave][16 + col16][nj * 16 + g * 4]) = pb1;
        }

        __builtin_amdgcn_s_setprio(1);
        #pragma unroll
        for (int hh = 0; hh < 2; ++hh)
            #pragma unroll
            for (int kh = 0; kh < 2; ++kh) {
                const bf16x8 pa = *(const bf16x8*)(&Pt[wave][hh * 16 + col16][kh * 32 + g * 8]);
                #pragma unroll
                for (int nd = 0; nd < 4; ++nd)
                    o[hh][nd] = mfma16(vb[nd * 2 + kh], pa, o[hh][nd]);
            }
        __builtin_amdgcn_s_setprio(0);
    };

    loadK(kbA, 0);
    for (int it = 0; it < 32; it += 2) {
        body2(kbA, kbB, pnB, pnA, it);       // stores pnB (it-1), makes pnA (it)
        body2(kbB, kbA, pnA, pnB, it + 1);   // stores pnA (it), makes pnB (it+1)
    }
    // epilogue: store last iteration's P (it=31, in pnB)
    {
        const int kkp = 31 << 6;
        #pragma unroll
        for (int hh = 0; hh < 2; ++hh)
            #pragma unroll
            for (int nj = 0; nj < 4; ++nj)
                __builtin_nontemporal_store(pnB[hh][nj],
                    (f32x4*)(awp[hh] + kkp + nj * 16 + g * 4));
    }

    // ctx (B,S,D) bf16
    #pragma unroll
    for (int hh = 0; hh < 2; ++hh) {
        bf16_t* cp = ctx + ((size_t)b * S_LEN + q0 + hh * 16 + col16) * DMODEL + h * HDIM;
        #pragma unroll
        for (int nd = 0; nd < 4; ++nd) {
            bf16x4 cv;
            #pragma unroll
            for (int r = 0; r < 4; ++r) cv[r] = (bf16_t)o[hh][nd][r];
            *(bf16x4*)(cp + nd * 16 + g * 4) = cv;
        }
    }
}

// ---------------------------------------------------------------------------
extern "C" void kernel_launch(void* const* d_in, const int* in_sizes, int n_in,
                              void* d_out, int out_size, void* d_ws, size_t ws_size,
                              hipStream_t stream) {
    const float* x    = (const float*)d_in[0];
    const float* mask = (const float*)d_in[1];
    const float* wq   = (const float*)d_in[2];
    const float* bq   = (const float*)d_in[3];
    const float* wk   = (const float*)d_in[4];
    const float* bk   = (const float*)d_in[5];
    const float* wv   = (const float*)d_in[6];
    const float* bv   = (const float*)d_in[7];
    const float* wo   = (const float*)d_in[8];
    const float* bo   = (const float*)d_in[9];

    const size_t nX = (size_t)BSZ * S_LEN * DMODEL;      // 8388608
    const size_t nW = (size_t)DMODEL * DMODEL;           // 1048576

    char* ws = (char*)d_ws;
    size_t off = 0;
    bf16_t* xb     = (bf16_t*)(ws + off); off += nX * 2;
    bf16_t* wqkvT  = (bf16_t*)(ws + off); off += 3 * nW * 2;
    bf16_t* woT    = (bf16_t*)(ws + off); off += nW * 2;
    bf16_t* qbh    = (bf16_t*)(ws + off); off += nX * 2;
    bf16_t* kbh    = (bf16_t*)(ws + off); off += nX * 2;
    bf16_t* vrow   = (bf16_t*)(ws + off); off += nX * 2;
    bf16_t* vtb    = (bf16_t*)(ws + off); off += nX * 2;
    bf16_t* ctx    = (bf16_t*)(ws + off); off += nX * 2;
    if (ws_size < off) return;  // workspace too small: loud failure (output stays zero)

    float* outp  = (float*)d_out;
    float* attnW = outp + nX;  // out is B*S*D, then attn weights B*H*S*S

    cvt_x_kernel<<<4096, 256, 0, stream>>>(x, xb, (int)(nX / 4));
    cvt_wT_kernel<<<dim3(16, 16), 256, 0, stream>>>(wq, wqkvT);
    cvt_wT_kernel<<<dim3(16, 16), 256, 0, stream>>>(wk, wqkvT + nW);
    cvt_wT_kernel<<<dim3(16, 16), 256, 0, stream>>>(wv, wqkvT + 2 * nW);
    cvt_wT_kernel<<<dim3(16, 16), 256, 0, stream>>>(wo, woT);

    gemm_bt<0><<<dim3(24, 64), 256, 0, stream>>>(xb, wqkvT, bq, bk, bv,
                                                 qbh, kbh, vrow, nullptr);
    transpose_v<<<dim3(32, 64), 256, 0, stream>>>(vrow, vtb);

    attn_fused<<<dim3(16, 64), 256, 0, stream>>>(qbh, kbh, vtb, mask, attnW, ctx);

    gemm_bt<2><<<dim3(8, 64), 256, 0, stream>>>(ctx, woT, bo, nullptr, nullptr,
                                                nullptr, nullptr, nullptr, outp);
}

// Round 10
// 403.581 us; speedup vs baseline: 1.9788x; 1.3627x over previous
//
#include <hip/hip_runtime.h>
#include <hip/hip_bf16.h>

// Problem constants: B=4, S=2048, D=1024, H=16, HD=64
#define S_LEN  2048
#define DMODEL 1024
#define NHEAD  16
#define HDIM   64
#define BSZ    4

// exp2-domain softmax constants
#define C_SCORE  0.18033688f        // 0.125 * log2(e)
#define C_MASK  -1.4426950e9f       // -1e9 * log2(e)

typedef __bf16 bf16_t;
typedef __bf16 bf16x8 __attribute__((ext_vector_type(8)));
typedef __bf16 bf16x4 __attribute__((ext_vector_type(4)));
typedef float  f32x4  __attribute__((ext_vector_type(4)));

typedef __attribute__((address_space(1))) void as1_void;
typedef __attribute__((address_space(3))) void as3_void;

__device__ __forceinline__ f32x4 mfma16(bf16x8 a, bf16x8 b, f32x4 c) {
    return __builtin_amdgcn_mfma_f32_16x16x32_bf16(a, b, c, 0, 0, 0);
}

// ---------------------------------------------------------------------------
__global__ __launch_bounds__(256) void cvt_x_kernel(const float* __restrict__ x,
                                                    bf16_t* __restrict__ xb, int n4) {
    int i = blockIdx.x * 256 + threadIdx.x;
    int stride = gridDim.x * 256;
    for (; i < n4; i += stride) {
        float4 v = ((const float4*)x)[i];
        bf16x4 t = { (bf16_t)v.x, (bf16_t)v.y, (bf16_t)v.z, (bf16_t)v.w };
        ((bf16x4*)xb)[i] = t;
    }
}

__global__ __launch_bounds__(256) void cvt_wT_kernel(const float* __restrict__ w,
                                                     bf16_t* __restrict__ wT) {
    __shared__ bf16_t t[64][65];
    const int bx = blockIdx.x * 64;
    const int by = blockIdx.y * 64;
    const int tx = threadIdx.x & 63, ty = threadIdx.x >> 6;
    #pragma unroll
    for (int rr = 0; rr < 64; rr += 4)
        t[tx][rr + ty] = (bf16_t)w[(size_t)(bx + rr + ty) * DMODEL + by + tx];
    __syncthreads();
    #pragma unroll
    for (int rr = 0; rr < 64; rr += 4)
        wT[(size_t)(by + rr + ty) * DMODEL + bx + tx] = t[rr + ty][tx];
}

__global__ __launch_bounds__(256) void transpose_v(const bf16_t* __restrict__ V,
                                                   bf16_t* __restrict__ Vt) {
    __shared__ __attribute__((aligned(16))) bf16_t t[64][72];
    const int bh = blockIdx.y;
    const int s0 = blockIdx.x * 64;
    const int tid = threadIdx.x;
    const bf16_t* Vb = V + (size_t)bh * S_LEN * HDIM;
    bf16_t* Vo = Vt + (size_t)bh * HDIM * S_LEN;
    #pragma unroll
    for (int p = 0; p < 2; ++p) {
        const int sl = p * 32 + (tid >> 3);
        const int c8 = (tid & 7) * 8;
        bf16x8 v = *(const bf16x8*)(Vb + (size_t)(s0 + sl) * HDIM + c8);
        #pragma unroll
        for (int j = 0; j < 8; ++j) t[c8 + j][sl] = v[j];
    }
    __syncthreads();
    #pragma unroll
    for (int p = 0; p < 2; ++p) {
        const int dl = p * 32 + (tid >> 3);
        const int s8 = (tid & 7) * 8;
        bf16x8 v = *(const bf16x8*)(&t[dl][s8]);
        *(bf16x8*)(Vo + (size_t)dl * S_LEN + s0 + s8) = v;
    }
}

// ---------------------------------------------------------------------------
// GEMM: C = A(Mx1024) * Bt(Nx1024)^T + bias. 128x128 tile, 4 waves (2x2).
// MODE 0: fused QKV (N=3072): Q,K,V bf16 (B,H,S,HD) row-major.
// MODE 2: out-projection (N=1024): fp32 (B,S,D).
template <int MODE>
__global__ __launch_bounds__(256) void gemm_bt(const bf16_t* __restrict__ A,
                                               const bf16_t* __restrict__ Bt,
                                               const float* __restrict__ b0,
                                               const float* __restrict__ b1,
                                               const float* __restrict__ b2,
                                               bf16_t* __restrict__ o0,
                                               bf16_t* __restrict__ o1,
                                               bf16_t* __restrict__ o2,
                                               float* __restrict__ of) {
    constexpr int GK = 1024;
    __shared__ __attribute__((aligned(16))) bf16_t As[128 * 32];
    __shared__ __attribute__((aligned(16))) bf16_t Bs[128 * 32];

    const int tid  = threadIdx.x;
    const int wave = tid >> 6, lane = tid & 63;
    const int col16 = lane & 15, g = lane >> 4;
    const int wr = wave >> 1, wc = wave & 1;
    const int bn0 = blockIdx.x * 128, bm0 = blockIdx.y * 128;

    const int r4 = tid >> 2;
    const int c8 = (tid & 3) * 8;

    f32x4 acc[4][4] = {};

    for (int k0 = 0; k0 < GK; k0 += 32) {
        __syncthreads();
        #pragma unroll
        for (int i = 0; i < 2; ++i) {
            __builtin_amdgcn_global_load_lds(
                (const as1_void*)(A + (size_t)(bm0 + i * 64 + r4) * GK + k0 + c8),
                (as3_void*)(As + (i * 64 + wave * 16) * 32), 16, 0, 0);
            __builtin_amdgcn_global_load_lds(
                (const as1_void*)(Bt + (size_t)(bn0 + i * 64 + r4) * GK + k0 + c8),
                (as3_void*)(Bs + (i * 64 + wave * 16) * 32), 16, 0, 0);
        }
        __syncthreads();

        bf16x8 af[4], bfr[4];
        #pragma unroll
        for (int i = 0; i < 4; ++i) {
            af[i]  = *(const bf16x8*)(As + (wr * 64 + i * 16 + col16) * 32 + g * 8);
            bfr[i] = *(const bf16x8*)(Bs + (wc * 64 + i * 16 + col16) * 32 + g * 8);
        }
        #pragma unroll
        for (int mi = 0; mi < 4; ++mi)
            #pragma unroll
            for (int ni = 0; ni < 4; ++ni)
                acc[mi][ni] = mfma16(af[mi], bfr[ni], acc[mi][ni]);
    }

    #pragma unroll
    for (int ni = 0; ni < 4; ++ni) {
        const int gn = bn0 + wc * 64 + ni * 16 + col16;
        if (MODE == 0) {
            const int proj = bn0 >> 10;
            const float* bias = proj == 0 ? b0 : (proj == 1 ? b1 : b2);
            bf16_t* outp      = proj == 0 ? o0 : (proj == 1 ? o1 : o2);
            const int n1 = gn & 1023, h = n1 >> 6, hd = n1 & 63;
            const float bv = bias[n1];
            #pragma unroll
            for (int mi = 0; mi < 4; ++mi)
                #pragma unroll
                for (int r = 0; r < 4; ++r) {
                    const int gm = bm0 + wr * 64 + mi * 16 + g * 4 + r;
                    const int b = gm >> 11, s = gm & 2047;
                    outp[(((size_t)b * NHEAD + h) * S_LEN + s) * HDIM + hd] =
                        (bf16_t)(acc[mi][ni][r] + bv);
                }
        } else {
            const float bv = b0[gn];
            #pragma unroll
            for (int mi = 0; mi < 4; ++mi)
                #pragma unroll
                for (int r = 0; r < 4; ++r) {
                    const int gm = bm0 + wr * 64 + mi * 16 + g * 4 + r;
                    of[(size_t)gm * DMODEL + gn] = acc[mi][ni][r] + bv;
                }
        }
    }
}

// ---------------------------------------------------------------------------
// Fused attention v10: LDS-staged K/V + coalesced stores.
// Structural fix for the r2-r9 plateau: every mem instr touched 16 cache
// lines and all 4 waves loaded the same K/V redundantly. Now:
//  - K,V staged in LDS via global_load_lds (dbuf, cooperative, coalesced
//    full lines, async = no VGPR cost). XOR swizzle (unit p = u ^ (row&7))
//    applied via pre-swizzled GLOBAL source + linear LDS dest (rule #21);
//    ds_read_b128 fragments land at the minimal 8-lane/bank-group pattern.
//  - P fp32 round-trips wave-private LDS (Pl, same swizzle) so attnW stores
//    are 4 rows x 256B = 8 FULL 128B lines per instruction (was 16 half
//    lines). PV operand is cvt'd from the same Pl data (no separate Pt).
//  - m201-style counted vmcnt: stages issued BEFORE stores; end-of-iteration
//    s_waitcnt vmcnt(8) + raw s_barrier => stages guaranteed landed, current
//    stores NEVER force-drained (they ride >=1 iteration in background).
//    PV reads V from LDS, so no global-consume wait sits behind stores.
__global__ __launch_bounds__(256, 2) void attn_fused(const bf16_t* __restrict__ Q,
                                                     const bf16_t* __restrict__ K,
                                                     const bf16_t* __restrict__ Vt,
                                                     const float* __restrict__ mask,
                                                     float* __restrict__ attnW,
                                                     bf16_t* __restrict__ ctx) {
    __shared__ __attribute__((aligned(16))) bf16_t Ks[2][64][64];  // 16 KB
    __shared__ __attribute__((aligned(16))) bf16_t Vs[2][64][64];  // 16 KB
    __shared__ __attribute__((aligned(16))) float  Pl[4][32][64];  // 32 KB

    const int tid = threadIdx.x, wave = tid >> 6, lane = tid & 63;
    const int col16 = lane & 15, g = lane >> 4;
    const int r7 = col16 & 7;

    // bijective XCD swizzle (1024 blocks, 1024 % 8 == 0)
    const int lin = blockIdx.y * 16 + blockIdx.x;
    const int logical = (lin & 7) * 128 + (lin >> 3);
    const int bh = logical >> 4, qt = logical & 15;
    const int b = bh >> 4, h = bh & 15;
    const int q0 = qt * 128 + wave * 32;

    const bf16_t* Qb = Q + (size_t)bh * S_LEN * HDIM;
    const bf16_t* Kb = K + (size_t)bh * S_LEN * HDIM;
    const bf16_t* Vb = Vt + (size_t)bh * HDIM * S_LEN;
    const float* mp = mask + (size_t)b * S_LEN;

    // staging lane constants: linear LDS slot (lane*16B), pre-swizzled source
    const int srow  = lane >> 3;            // row within 8-row chunk
    const int sunit = (lane & 7) ^ srow;    // logical 16B-unit fetched for this slot

    auto stageK = [&](int buf, int it) {
        const int kk0 = it << 6;
        #pragma unroll
        for (int i2 = 0; i2 < 2; ++i2) {
            const int i = wave * 2 + i2;   // chunk 0..7 (8 rows x 128B each)
            __builtin_amdgcn_global_load_lds(
                (const as1_void*)(Kb + (size_t)(kk0 + i * 8 + srow) * HDIM + sunit * 8),
                (as3_void*)(&Ks[buf][i * 8][0]), 16, 0, 0);
        }
    };
    auto stageV = [&](int buf, int it) {
        const int kk0 = it << 6;
        #pragma unroll
        for (int i2 = 0; i2 < 2; ++i2) {
            const int i = wave * 2 + i2;
            __builtin_amdgcn_global_load_lds(
                (const as1_void*)(Vb + (size_t)(i * 8 + srow) * S_LEN + kk0 + sunit * 8),
                (as3_void*)(&Vs[buf][i * 8][0]), 16, 0, 0);
        }
    };
    // fragment reads: logical unit u at physical p = u ^ (row&7); row&7 == col16&7
    auto kfrag = [&](int buf, int nj, int kh) {
        return *(const bf16x8*)(&Ks[buf][nj * 16 + col16][(((kh * 4 + g) ^ r7) * 8)]);
    };
    auto vfrag = [&](int buf, int nd, int kh) {
        return *(const bf16x8*)(&Vs[buf][nd * 16 + col16][(((kh * 4 + g) ^ r7) * 8)]);
    };

    // Q B-frags for both 16-row halves
    bf16x8 qa[2][2];
    #pragma unroll
    for (int hh = 0; hh < 2; ++hh)
        #pragma unroll
        for (int kh = 0; kh < 2; ++kh)
            qa[hh][kh] = *(const bf16x8*)(Qb + (size_t)(q0 + hh * 16 + col16) * HDIM +
                                          kh * 32 + g * 8);

    // ================= sweep 1: l only =================
    f32x4 lacc[2] = {};

    stageK(0, 0);
    asm volatile("s_waitcnt vmcnt(0)" ::: "memory");
    __builtin_amdgcn_sched_barrier(0);
    __builtin_amdgcn_s_barrier();

    for (int it = 0; it < 32; ++it) {
        const int kk0 = it << 6, cur = it & 1;
        f32x4 mvr[4];
        #pragma unroll
        for (int nj = 0; nj < 4; ++nj) mvr[nj] = ((const f32x4*)(mp + kk0 + nj * 16))[g];
        if (it < 31) stageK(cur ^ 1, it + 1);
        #pragma unroll
        for (int nj = 0; nj < 4; ++nj) {
            const bf16x8 kf0 = kfrag(cur, nj, 0);
            const bf16x8 kf1 = kfrag(cur, nj, 1);
            f32x4 t0 = {0.f, 0.f, 0.f, 0.f}, t1 = {0.f, 0.f, 0.f, 0.f};
            t0 = mfma16(kf0, qa[0][0], t0);
            t0 = mfma16(kf1, qa[0][1], t0);
            t1 = mfma16(kf0, qa[1][0], t1);
            t1 = mfma16(kf1, qa[1][1], t1);
            #pragma unroll
            for (int r = 0; r < 4; ++r) {
                const float mm = mvr[nj][r] * C_MASK;
                lacc[0][r] += exp2f(fmaf(t0[r], C_SCORE, mm));
                lacc[1][r] += exp2f(fmaf(t1[r], C_SCORE, mm));
            }
        }
        asm volatile("s_waitcnt vmcnt(0)" ::: "memory");
        __builtin_amdgcn_sched_barrier(0);
        __builtin_amdgcn_s_barrier();
    }

    float crow[2];
    #pragma unroll
    for (int hh = 0; hh < 2; ++hh) {
        float lr = (lacc[hh][0] + lacc[hh][1]) + (lacc[hh][2] + lacc[hh][3]);
        lr += __shfl_xor(lr, 16);
        lr += __shfl_xor(lr, 32);
        crow[hh] = -__log2f(lr);
    }

    // ================= sweep 2: normalized weights + PV =================
    f32x4 o[2][4] = {};
    float* awbase = attnW + ((size_t)bh * S_LEN + q0) * S_LEN;

    stageK(0, 0);
    stageV(0, 0);
    asm volatile("s_waitcnt vmcnt(0)" ::: "memory");
    __builtin_amdgcn_sched_barrier(0);
    __builtin_amdgcn_s_barrier();

    for (int it = 0; it < 32; ++it) {
        const int kk0 = it << 6, cur = it & 1;
        f32x4 mvr[4];
        #pragma unroll
        for (int nj = 0; nj < 4; ++nj) mvr[nj] = ((const f32x4*)(mp + kk0 + nj * 16))[g];
        if (it < 31) { stageK(cur ^ 1, it + 1); stageV(cur ^ 1, it + 1); }

        // QK^T -> exp2 -> Pl (wave-private, swizzled)
        #pragma unroll
        for (int nj = 0; nj < 4; ++nj) {
            const bf16x8 kf0 = kfrag(cur, nj, 0);
            const bf16x8 kf1 = kfrag(cur, nj, 1);
            f32x4 t0 = {0.f, 0.f, 0.f, 0.f}, t1 = {0.f, 0.f, 0.f, 0.f};
            t0 = mfma16(kf0, qa[0][0], t0);
            t0 = mfma16(kf1, qa[0][1], t0);
            t1 = mfma16(kf0, qa[1][0], t1);
            t1 = mfma16(kf1, qa[1][1], t1);
            f32x4 pn0, pn1;
            #pragma unroll
            for (int r = 0; r < 4; ++r) {
                const float mm = mvr[nj][r] * C_MASK;
                pn0[r] = exp2f(fmaf(t0[r], C_SCORE, mm + crow[0]));
                pn1[r] = exp2f(fmaf(t1[r], C_SCORE, mm + crow[1]));
            }
            const int pw = ((nj * 4 + g) ^ r7) * 4;
            *(f32x4*)(&Pl[wave][col16][pw])      = pn0;
            *(f32x4*)(&Pl[wave][16 + col16][pw]) = pn1;
        }

        // coalesced nt-stores: 8 instrs, each 4 rows x 256B = 8 full lines
        #pragma unroll
        for (int j = 0; j < 8; ++j) {
            const int row = j * 4 + (lane >> 4);
            const int u = lane & 15;
            const f32x4 v = *(const f32x4*)(&Pl[wave][row][((u ^ (row & 7)) * 4)]);
            __builtin_nontemporal_store(v, (f32x4*)(awbase + (size_t)row * S_LEN + kk0 + u * 4));
        }

        // PV from LDS (V frags + P cvt'd from Pl) — no global waits here
        #pragma unroll
        for (int hh = 0; hh < 2; ++hh)
            #pragma unroll
            for (int kh = 0; kh < 2; ++kh) {
                const int u0 = kh * 8 + g * 2;
                const f32x4 a0 = *(const f32x4*)(&Pl[wave][hh * 16 + col16][((u0 ^ r7) * 4)]);
                const f32x4 a1 = *(const f32x4*)(&Pl[wave][hh * 16 + col16][(((u0 + 1) ^ r7) * 4)]);
                bf16x8 pa;
                #pragma unroll
                for (int j = 0; j < 4; ++j) {
                    pa[j]     = (bf16_t)a0[j];
                    pa[4 + j] = (bf16_t)a1[j];
                }
                #pragma unroll
                for (int nd = 0; nd < 4; ++nd)
                    o[hh][nd] = mfma16(vfrag(cur, nd, kh), pa, o[hh][nd]);
            }

        // stages (older than stores) guaranteed landed; stores(it) stay in flight
        asm volatile("s_waitcnt vmcnt(8)" ::: "memory");
        __builtin_amdgcn_sched_barrier(0);
        __builtin_amdgcn_s_barrier();
    }

    // ctx (B,S,D) bf16
    #pragma unroll
    for (int hh = 0; hh < 2; ++hh) {
        bf16_t* cp = ctx + ((size_t)b * S_LEN + q0 + hh * 16 + col16) * DMODEL + h * HDIM;
        #pragma unroll
        for (int nd = 0; nd < 4; ++nd) {
            bf16x4 cv;
            #pragma unroll
            for (int r = 0; r < 4; ++r) cv[r] = (bf16_t)o[hh][nd][r];
            *(bf16x4*)(cp + nd * 16 + g * 4) = cv;
        }
    }
}

// ---------------------------------------------------------------------------
extern "C" void kernel_launch(void* const* d_in, const int* in_sizes, int n_in,
                              void* d_out, int out_size, void* d_ws, size_t ws_size,
                              hipStream_t stream) {
    const float* x    = (const float*)d_in[0];
    const float* mask = (const float*)d_in[1];
    const float* wq   = (const float*)d_in[2];
    const float* bq   = (const float*)d_in[3];
    const float* wk   = (const float*)d_in[4];
    const float* bk   = (const float*)d_in[5];
    const float* wv   = (const float*)d_in[6];
    const float* bv   = (const float*)d_in[7];
    const float* wo   = (const float*)d_in[8];
    const float* bo   = (const float*)d_in[9];

    const size_t nX = (size_t)BSZ * S_LEN * DMODEL;      // 8388608
    const size_t nW = (size_t)DMODEL * DMODEL;           // 1048576

    char* ws = (char*)d_ws;
    size_t off = 0;
    bf16_t* xb     = (bf16_t*)(ws + off); off += nX * 2;
    bf16_t* wqkvT  = (bf16_t*)(ws + off); off += 3 * nW * 2;
    bf16_t* woT    = (bf16_t*)(ws + off); off += nW * 2;
    bf16_t* qbh    = (bf16_t*)(ws + off); off += nX * 2;
    bf16_t* kbh    = (bf16_t*)(ws + off); off += nX * 2;
    bf16_t* vrow   = (bf16_t*)(ws + off); off += nX * 2;
    bf16_t* vtb    = (bf16_t*)(ws + off); off += nX * 2;
    bf16_t* ctx    = (bf16_t*)(ws + off); off += nX * 2;
    if (ws_size < off) return;  // workspace too small: loud failure (output stays zero)

    float* outp  = (float*)d_out;
    float* attnW = outp + nX;  // out is B*S*D, then attn weights B*H*S*S

    cvt_x_kernel<<<4096, 256, 0, stream>>>(x, xb, (int)(nX / 4));
    cvt_wT_kernel<<<dim3(16, 16), 256, 0, stream>>>(wq, wqkvT);
    cvt_wT_kernel<<<dim3(16, 16), 256, 0, stream>>>(wk, wqkvT + nW);
    cvt_wT_kernel<<<dim3(16, 16), 256, 0, stream>>>(wv, wqkvT + 2 * nW);
    cvt_wT_kernel<<<dim3(16, 16), 256, 0, stream>>>(wo, woT);

    gemm_bt<0><<<dim3(24, 64), 256, 0, stream>>>(xb, wqkvT, bq, bk, bv,
                                                 qbh, kbh, vrow, nullptr);
    transpose_v<<<dim3(32, 64), 256, 0, stream>>>(vrow, vtb);

    attn_fused<<<dim3(16, 64), 256, 0, stream>>>(qbh, kbh, vtb, mask, attnW, ctx);

    gemm_bt<2><<<dim3(8, 64), 256, 0, stream>>>(ctx, woT, bo, nullptr, nullptr,
                                                nullptr, nullptr, nullptr, outp);
}

// Round 11
// 382.670 us; speedup vs baseline: 2.0869x; 1.0546x over previous
//
#include <hip/hip_runtime.h>
#include <hip/hip_bf16.h>

// Problem constants: B=4, S=2048, D=1024, H=16, HD=64
#define S_LEN  2048
#define DMODEL 1024
#define NHEAD  16
#define HDIM   64
#define BSZ    4

// exp2-domain softmax constants
#define C_SCORE  0.18033688f        // 0.125 * log2(e)
#define C_MASK  -1.4426950e9f       // -1e9 * log2(e)

typedef __bf16 bf16_t;
typedef __bf16 bf16x8 __attribute__((ext_vector_type(8)));
typedef __bf16 bf16x4 __attribute__((ext_vector_type(4)));
typedef float  f32x4  __attribute__((ext_vector_type(4)));

typedef __attribute__((address_space(1))) void as1_void;
typedef __attribute__((address_space(3))) void as3_void;

__device__ __forceinline__ f32x4 mfma16(bf16x8 a, bf16x8 b, f32x4 c) {
    return __builtin_amdgcn_mfma_f32_16x16x32_bf16(a, b, c, 0, 0, 0);
}

// ---------------------------------------------------------------------------
__global__ __launch_bounds__(256) void cvt_x_kernel(const float* __restrict__ x,
                                                    bf16_t* __restrict__ xb, int n4) {
    int i = blockIdx.x * 256 + threadIdx.x;
    int stride = gridDim.x * 256;
    for (; i < n4; i += stride) {
        float4 v = ((const float4*)x)[i];
        bf16x4 t = { (bf16_t)v.x, (bf16_t)v.y, (bf16_t)v.z, (bf16_t)v.w };
        ((bf16x4*)xb)[i] = t;
    }
}

__global__ __launch_bounds__(256) void cvt_wT_kernel(const float* __restrict__ w,
                                                     bf16_t* __restrict__ wT) {
    __shared__ bf16_t t[64][65];
    const int bx = blockIdx.x * 64;
    const int by = blockIdx.y * 64;
    const int tx = threadIdx.x & 63, ty = threadIdx.x >> 6;
    #pragma unroll
    for (int rr = 0; rr < 64; rr += 4)
        t[tx][rr + ty] = (bf16_t)w[(size_t)(bx + rr + ty) * DMODEL + by + tx];
    __syncthreads();
    #pragma unroll
    for (int rr = 0; rr < 64; rr += 4)
        wT[(size_t)(by + rr + ty) * DMODEL + bx + tx] = t[rr + ty][tx];
}

__global__ __launch_bounds__(256) void transpose_v(const bf16_t* __restrict__ V,
                                                   bf16_t* __restrict__ Vt) {
    __shared__ __attribute__((aligned(16))) bf16_t t[64][72];
    const int bh = blockIdx.y;
    const int s0 = blockIdx.x * 64;
    const int tid = threadIdx.x;
    const bf16_t* Vb = V + (size_t)bh * S_LEN * HDIM;
    bf16_t* Vo = Vt + (size_t)bh * HDIM * S_LEN;
    #pragma unroll
    for (int p = 0; p < 2; ++p) {
        const int sl = p * 32 + (tid >> 3);
        const int c8 = (tid & 7) * 8;
        bf16x8 v = *(const bf16x8*)(Vb + (size_t)(s0 + sl) * HDIM + c8);
        #pragma unroll
        for (int j = 0; j < 8; ++j) t[c8 + j][sl] = v[j];
    }
    __syncthreads();
    #pragma unroll
    for (int p = 0; p < 2; ++p) {
        const int dl = p * 32 + (tid >> 3);
        const int s8 = (tid & 7) * 8;
        bf16x8 v = *(const bf16x8*)(&t[dl][s8]);
        *(bf16x8*)(Vo + (size_t)dl * S_LEN + s0 + s8) = v;
    }
}

// ---------------------------------------------------------------------------
// GEMM: C = A(Mx1024) * Bt(Nx1024)^T + bias. 128x128 tile, 4 waves (2x2).
// MODE 0: fused QKV (N=3072): Q,K,V bf16 (B,H,S,HD) row-major.
// MODE 2: out-projection (N=1024): fp32 (B,S,D).
template <int MODE>
__global__ __launch_bounds__(256) void gemm_bt(const bf16_t* __restrict__ A,
                                               const bf16_t* __restrict__ Bt,
                                               const float* __restrict__ b0,
                                               const float* __restrict__ b1,
                                               const float* __restrict__ b2,
                                               bf16_t* __restrict__ o0,
                                               bf16_t* __restrict__ o1,
                                               bf16_t* __restrict__ o2,
                                               float* __restrict__ of) {
    constexpr int GK = 1024;
    __shared__ __attribute__((aligned(16))) bf16_t As[128 * 32];
    __shared__ __attribute__((aligned(16))) bf16_t Bs[128 * 32];

    const int tid  = threadIdx.x;
    const int wave = tid >> 6, lane = tid & 63;
    const int col16 = lane & 15, g = lane >> 4;
    const int wr = wave >> 1, wc = wave & 1;
    const int bn0 = blockIdx.x * 128, bm0 = blockIdx.y * 128;

    const int r4 = tid >> 2;
    const int c8 = (tid & 3) * 8;

    f32x4 acc[4][4] = {};

    for (int k0 = 0; k0 < GK; k0 += 32) {
        __syncthreads();
        #pragma unroll
        for (int i = 0; i < 2; ++i) {
            __builtin_amdgcn_global_load_lds(
                (const as1_void*)(A + (size_t)(bm0 + i * 64 + r4) * GK + k0 + c8),
                (as3_void*)(As + (i * 64 + wave * 16) * 32), 16, 0, 0);
            __builtin_amdgcn_global_load_lds(
                (const as1_void*)(Bt + (size_t)(bn0 + i * 64 + r4) * GK + k0 + c8),
                (as3_void*)(Bs + (i * 64 + wave * 16) * 32), 16, 0, 0);
        }
        __syncthreads();

        bf16x8 af[4], bfr[4];
        #pragma unroll
        for (int i = 0; i < 4; ++i) {
            af[i]  = *(const bf16x8*)(As + (wr * 64 + i * 16 + col16) * 32 + g * 8);
            bfr[i] = *(const bf16x8*)(Bs + (wc * 64 + i * 16 + col16) * 32 + g * 8);
        }
        #pragma unroll
        for (int mi = 0; mi < 4; ++mi)
            #pragma unroll
            for (int ni = 0; ni < 4; ++ni)
                acc[mi][ni] = mfma16(af[mi], bfr[ni], acc[mi][ni]);
    }

    #pragma unroll
    for (int ni = 0; ni < 4; ++ni) {
        const int gn = bn0 + wc * 64 + ni * 16 + col16;
        if (MODE == 0) {
            const int proj = bn0 >> 10;
            const float* bias = proj == 0 ? b0 : (proj == 1 ? b1 : b2);
            bf16_t* outp      = proj == 0 ? o0 : (proj == 1 ? o1 : o2);
            const int n1 = gn & 1023, h = n1 >> 6, hd = n1 & 63;
            const float bv = bias[n1];
            #pragma unroll
            for (int mi = 0; mi < 4; ++mi)
                #pragma unroll
                for (int r = 0; r < 4; ++r) {
                    const int gm = bm0 + wr * 64 + mi * 16 + g * 4 + r;
                    const int b = gm >> 11, s = gm & 2047;
                    outp[(((size_t)b * NHEAD + h) * S_LEN + s) * HDIM + hd] =
                        (bf16_t)(acc[mi][ni][r] + bv);
                }
        } else {
            const float bv = b0[gn];
            #pragma unroll
            for (int mi = 0; mi < 4; ++mi)
                #pragma unroll
                for (int r = 0; r < 4; ++r) {
                    const int gm = bm0 + wr * 64 + mi * 16 + g * 4 + r;
                    of[(size_t)gm * DMODEL + gn] = acc[mi][ni][r] + bv;
                }
        }
    }
}

// ---------------------------------------------------------------------------
// Fused attention v11: v10 LDS-staged skeleton + 2-tile phase pipeline.
// Each block owns TWO 128-row q-tiles (qA, qB) of one head:
//   loop A: l(qA) only, K staged (compute-only; no stores).
//   loop B: ONE K+V stage stream serves BOTH tile0's store sweep
//           (exp2 -> Pl -> coalesced nt-stores -> PV) AND tile1's
//           l-accumulation -> tile1's l-pass rides under store pacing.
//   loop C: store sweep for tile1.
// Per 2 tiles: 96 loop iterations (was 128), one K stream eliminated.
// Mask is pre-scaled by C_MASK into LDS once -> per-iter VMEM stream is
// exactly [4 stages][8 stores] so the counted vmcnt(8) at each barrier
// guarantees stages landed while this iteration's stores stay in flight.
// LDS: Ks 16K + Vs 16K + Pl 32K + Ml 8K = 72 KB -> 2 blocks/CU.
__global__ __launch_bounds__(256, 2) void attn_fused(const bf16_t* __restrict__ Q,
                                                     const bf16_t* __restrict__ K,
                                                     const bf16_t* __restrict__ Vt,
                                                     const float* __restrict__ mask,
                                                     float* __restrict__ attnW,
                                                     bf16_t* __restrict__ ctx) {
    __shared__ __attribute__((aligned(16))) bf16_t Ks[2][64][64];  // 16 KB
    __shared__ __attribute__((aligned(16))) bf16_t Vs[2][64][64];  // 16 KB
    __shared__ __attribute__((aligned(16))) float  Pl[4][32][64];  // 32 KB
    __shared__ __attribute__((aligned(16))) float  Ml[S_LEN];      //  8 KB

    const int tid = threadIdx.x, wave = tid >> 6, lane = tid & 63;
    const int col16 = lane & 15, g = lane >> 4;
    const int r7 = col16 & 7;

    // bijective XCD swizzle (512 blocks, 512 % 8 == 0): 8 heads per XCD
    const int lin = blockIdx.x;
    const int logical = (lin & 7) * 64 + (lin >> 3);
    const int bh = logical >> 3, pp = logical & 7;
    const int b = bh >> 4, h = bh & 15;
    const int qA = pp * 256 + wave * 32;
    const int qB = pp * 256 + 128 + wave * 32;

    const bf16_t* Qb = Q + (size_t)bh * S_LEN * HDIM;
    const bf16_t* Kb = K + (size_t)bh * S_LEN * HDIM;
    const bf16_t* Vb = Vt + (size_t)bh * HDIM * S_LEN;
    const float* mp = mask + (size_t)b * S_LEN;

    // mask * C_MASK -> LDS once (removes per-iter VMEM mask loads)
    #pragma unroll
    for (int i = 0; i < 2; ++i) {
        const int idx = i * 256 + tid;           // 512 f32x4 slots
        f32x4 v = ((const f32x4*)mp)[idx];
        #pragma unroll
        for (int r = 0; r < 4; ++r) v[r] *= C_MASK;
        *(f32x4*)(&Ml[idx * 4]) = v;
    }

    // staging lane constants: linear LDS dest, pre-swizzled global source
    const int srow  = lane >> 3;
    const int sunit = (lane & 7) ^ srow;

    auto stageK = [&](int buf, int it) {
        const int kk0 = it << 6;
        #pragma unroll
        for (int i2 = 0; i2 < 2; ++i2) {
            const int i = wave * 2 + i2;
            __builtin_amdgcn_global_load_lds(
                (const as1_void*)(Kb + (size_t)(kk0 + i * 8 + srow) * HDIM + sunit * 8),
                (as3_void*)(&Ks[buf][i * 8][0]), 16, 0, 0);
        }
    };
    auto stageV = [&](int buf, int it) {
        const int kk0 = it << 6;
        #pragma unroll
        for (int i2 = 0; i2 < 2; ++i2) {
            const int i = wave * 2 + i2;
            __builtin_amdgcn_global_load_lds(
                (const as1_void*)(Vb + (size_t)(i * 8 + srow) * S_LEN + kk0 + sunit * 8),
                (as3_void*)(&Vs[buf][i * 8][0]), 16, 0, 0);
        }
    };
    auto kfrag = [&](int buf, int nj, int kh) {
        return *(const bf16x8*)(&Ks[buf][nj * 16 + col16][(((kh * 4 + g) ^ r7) * 8)]);
    };
    auto vfrag = [&](int buf, int nd, int kh) {
        return *(const bf16x8*)(&Vs[buf][nd * 16 + col16][(((kh * 4 + g) ^ r7) * 8)]);
    };

    // Q B-frags for both tiles, both 16-row halves
    bf16x8 qa0[2][2], qa1[2][2];
    #pragma unroll
    for (int hh = 0; hh < 2; ++hh)
        #pragma unroll
        for (int kh = 0; kh < 2; ++kh) {
            qa0[hh][kh] = *(const bf16x8*)(Qb + (size_t)(qA + hh * 16 + col16) * HDIM +
                                           kh * 32 + g * 8);
            qa1[hh][kh] = *(const bf16x8*)(Qb + (size_t)(qB + hh * 16 + col16) * HDIM +
                                           kh * 32 + g * 8);
        }

    // ================= loop A: l(tile0), K staged =================
    f32x4 lacc[2] = {};
    stageK(0, 0);
    __syncthreads();   // one-time full drain: Ml fill + stage(0) ready

    for (int it = 0; it < 32; ++it) {
        const int kk0 = it << 6, cur = it & 1;
        if (it < 31) stageK(cur ^ 1, it + 1);
        f32x4 mvr[4];
        #pragma unroll
        for (int nj = 0; nj < 4; ++nj)
            mvr[nj] = *(const f32x4*)(&Ml[kk0 + nj * 16 + g * 4]);
        #pragma unroll
        for (int nj = 0; nj < 4; ++nj) {
            const bf16x8 kf0 = kfrag(cur, nj, 0);
            const bf16x8 kf1 = kfrag(cur, nj, 1);
            f32x4 t0 = {0.f, 0.f, 0.f, 0.f}, t1 = {0.f, 0.f, 0.f, 0.f};
            t0 = mfma16(kf0, qa0[0][0], t0);
            t0 = mfma16(kf1, qa0[0][1], t0);
            t1 = mfma16(kf0, qa0[1][0], t1);
            t1 = mfma16(kf1, qa0[1][1], t1);
            #pragma unroll
            for (int r = 0; r < 4; ++r) {
                lacc[0][r] += exp2f(fmaf(t0[r], C_SCORE, mvr[nj][r]));
                lacc[1][r] += exp2f(fmaf(t1[r], C_SCORE, mvr[nj][r]));
            }
        }
        asm volatile("s_waitcnt vmcnt(0)" ::: "memory");
        __builtin_amdgcn_sched_barrier(0);
        __builtin_amdgcn_s_barrier();
    }

    float crow0[2];
    #pragma unroll
    for (int hh = 0; hh < 2; ++hh) {
        float lr = (lacc[hh][0] + lacc[hh][1]) + (lacc[hh][2] + lacc[hh][3]);
        lr += __shfl_xor(lr, 16);
        lr += __shfl_xor(lr, 32);
        crow0[hh] = -__log2f(lr);
        lacc[hh] = (f32x4){0.f, 0.f, 0.f, 0.f};   // reuse for tile1
    }

    // ================= loop B: store(tile0) + l(tile1) =================
    f32x4 o[2][4] = {};
    float* awbase = attnW + ((size_t)bh * S_LEN + qA) * S_LEN;

    stageK(0, 0);
    stageV(0, 0);
    asm volatile("s_waitcnt vmcnt(0)" ::: "memory");
    __builtin_amdgcn_sched_barrier(0);
    __builtin_amdgcn_s_barrier();

    for (int it = 0; it < 32; ++it) {
        const int kk0 = it << 6, cur = it & 1;
        if (it < 31) { stageK(cur ^ 1, it + 1); stageV(cur ^ 1, it + 1); }
        f32x4 mvr[4];
        #pragma unroll
        for (int nj = 0; nj < 4; ++nj)
            mvr[nj] = *(const f32x4*)(&Ml[kk0 + nj * 16 + g * 4]);

        // both tiles' QK^T per nj: tile0 -> Pl, tile1 -> lacc
        #pragma unroll
        for (int nj = 0; nj < 4; ++nj) {
            const bf16x8 kf0 = kfrag(cur, nj, 0);
            const bf16x8 kf1 = kfrag(cur, nj, 1);
            f32x4 s0 = {0.f, 0.f, 0.f, 0.f}, s1 = {0.f, 0.f, 0.f, 0.f};
            f32x4 u0 = {0.f, 0.f, 0.f, 0.f}, u1 = {0.f, 0.f, 0.f, 0.f};
            s0 = mfma16(kf0, qa0[0][0], s0);
            s0 = mfma16(kf1, qa0[0][1], s0);
            s1 = mfma16(kf0, qa0[1][0], s1);
            s1 = mfma16(kf1, qa0[1][1], s1);
            u0 = mfma16(kf0, qa1[0][0], u0);
            u0 = mfma16(kf1, qa1[0][1], u0);
            u1 = mfma16(kf0, qa1[1][0], u1);
            u1 = mfma16(kf1, qa1[1][1], u1);
            f32x4 pn0, pn1;
            #pragma unroll
            for (int r = 0; r < 4; ++r) {
                const float mm = mvr[nj][r];
                pn0[r] = exp2f(fmaf(s0[r], C_SCORE, mm + crow0[0]));
                pn1[r] = exp2f(fmaf(s1[r], C_SCORE, mm + crow0[1]));
                lacc[0][r] += exp2f(fmaf(u0[r], C_SCORE, mm));
                lacc[1][r] += exp2f(fmaf(u1[r], C_SCORE, mm));
            }
            const int pw = ((nj * 4 + g) ^ r7) * 4;
            *(f32x4*)(&Pl[wave][col16][pw])      = pn0;
            *(f32x4*)(&Pl[wave][16 + col16][pw]) = pn1;
        }

        // coalesced nt-stores (tile0): 8 instrs x 8 full 128B lines
        #pragma unroll
        for (int j = 0; j < 8; ++j) {
            const int row = j * 4 + (lane >> 4);
            const int u = lane & 15;
            const f32x4 v = *(const f32x4*)(&Pl[wave][row][((u ^ (row & 7)) * 4)]);
            __builtin_nontemporal_store(v, (f32x4*)(awbase + (size_t)row * S_LEN + kk0 + u * 4));
        }

        // PV (tile0) from LDS
        #pragma unroll
        for (int hh = 0; hh < 2; ++hh)
            #pragma unroll
            for (int kh = 0; kh < 2; ++kh) {
                const int u0i = kh * 8 + g * 2;
                const f32x4 a0 = *(const f32x4*)(&Pl[wave][hh * 16 + col16][((u0i ^ r7) * 4)]);
                const f32x4 a1 = *(const f32x4*)(&Pl[wave][hh * 16 + col16][(((u0i + 1) ^ r7) * 4)]);
                bf16x8 pa;
                #pragma unroll
                for (int j = 0; j < 4; ++j) {
                    pa[j]     = (bf16_t)a0[j];
                    pa[4 + j] = (bf16_t)a1[j];
                }
                #pragma unroll
                for (int nd = 0; nd < 4; ++nd)
                    o[hh][nd] = mfma16(vfrag(cur, nd, kh), pa, o[hh][nd]);
            }

        asm volatile("s_waitcnt vmcnt(8)" ::: "memory");
        __builtin_amdgcn_sched_barrier(0);
        __builtin_amdgcn_s_barrier();
    }

    float crow1[2];
    #pragma unroll
    for (int hh = 0; hh < 2; ++hh) {
        float lr = (lacc[hh][0] + lacc[hh][1]) + (lacc[hh][2] + lacc[hh][3]);
        lr += __shfl_xor(lr, 16);
        lr += __shfl_xor(lr, 32);
        crow1[hh] = -__log2f(lr);
    }

    // ctx (tile0)
    #pragma unroll
    for (int hh = 0; hh < 2; ++hh) {
        bf16_t* cp = ctx + ((size_t)b * S_LEN + qA + hh * 16 + col16) * DMODEL + h * HDIM;
        #pragma unroll
        for (int nd = 0; nd < 4; ++nd) {
            bf16x4 cv;
            #pragma unroll
            for (int r = 0; r < 4; ++r) cv[r] = (bf16_t)o[hh][nd][r];
            *(bf16x4*)(cp + nd * 16 + g * 4) = cv;
        }
        o[hh][0] = o[hh][1] = o[hh][2] = o[hh][3] = (f32x4){0.f, 0.f, 0.f, 0.f};
    }

    // ================= loop C: store(tile1) =================
    awbase = attnW + ((size_t)bh * S_LEN + qB) * S_LEN;

    stageK(0, 0);
    stageV(0, 0);
    asm volatile("s_waitcnt vmcnt(0)" ::: "memory");
    __builtin_amdgcn_sched_barrier(0);
    __builtin_amdgcn_s_barrier();

    for (int it = 0; it < 32; ++it) {
        const int kk0 = it << 6, cur = it & 1;
        if (it < 31) { stageK(cur ^ 1, it + 1); stageV(cur ^ 1, it + 1); }
        f32x4 mvr[4];
        #pragma unroll
        for (int nj = 0; nj < 4; ++nj)
            mvr[nj] = *(const f32x4*)(&Ml[kk0 + nj * 16 + g * 4]);

        #pragma unroll
        for (int nj = 0; nj < 4; ++nj) {
            const bf16x8 kf0 = kfrag(cur, nj, 0);
            const bf16x8 kf1 = kfrag(cur, nj, 1);
            f32x4 t0 = {0.f, 0.f, 0.f, 0.f}, t1 = {0.f, 0.f, 0.f, 0.f};
            t0 = mfma16(kf0, qa1[0][0], t0);
            t0 = mfma16(kf1, qa1[0][1], t0);
            t1 = mfma16(kf0, qa1[1][0], t1);
            t1 = mfma16(kf1, qa1[1][1], t1);
            f32x4 pn0, pn1;
            #pragma unroll
            for (int r = 0; r < 4; ++r) {
                const float mm = mvr[nj][r];
                pn0[r] = exp2f(fmaf(t0[r], C_SCORE, mm + crow1[0]));
                pn1[r] = exp2f(fmaf(t1[r], C_SCORE, mm + crow1[1]));
            }
            const int pw = ((nj * 4 + g) ^ r7) * 4;
            *(f32x4*)(&Pl[wave][col16][pw])      = pn0;
            *(f32x4*)(&Pl[wave][16 + col16][pw]) = pn1;
        }

        #pragma unroll
        for (int j = 0; j < 8; ++j) {
            const int row = j * 4 + (lane >> 4);
            const int u = lane & 15;
            const f32x4 v = *(const f32x4*)(&Pl[wave][row][((u ^ (row & 7)) * 4)]);
            __builtin_nontemporal_store(v, (f32x4*)(awbase + (size_t)row * S_LEN + kk0 + u * 4));
        }

        #pragma unroll
        for (int hh = 0; hh < 2; ++hh)
            #pragma unroll
            for (int kh = 0; kh < 2; ++kh) {
                const int u0i = kh * 8 + g * 2;
                const f32x4 a0 = *(const f32x4*)(&Pl[wave][hh * 16 + col16][((u0i ^ r7) * 4)]);
                const f32x4 a1 = *(const f32x4*)(&Pl[wave][hh * 16 + col16][(((u0i + 1) ^ r7) * 4)]);
                bf16x8 pa;
                #pragma unroll
                for (int j = 0; j < 4; ++j) {
                    pa[j]     = (bf16_t)a0[j];
                    pa[4 + j] = (bf16_t)a1[j];
                }
                #pragma unroll
                for (int nd = 0; nd < 4; ++nd)
                    o[hh][nd] = mfma16(vfrag(cur, nd, kh), pa, o[hh][nd]);
            }

        asm volatile("s_waitcnt vmcnt(8)" ::: "memory");
        __builtin_amdgcn_sched_barrier(0);
        __builtin_amdgcn_s_barrier();
    }

    // ctx (tile1)
    #pragma unroll
    for (int hh = 0; hh < 2; ++hh) {
        bf16_t* cp = ctx + ((size_t)b * S_LEN + qB + hh * 16 + col16) * DMODEL + h * HDIM;
        #pragma unroll
        for (int nd = 0; nd < 4; ++nd) {
            bf16x4 cv;
            #pragma unroll
            for (int r = 0; r < 4; ++r) cv[r] = (bf16_t)o[hh][nd][r];
            *(bf16x4*)(cp + nd * 16 + g * 4) = cv;
        }
    }
}

// ---------------------------------------------------------------------------
extern "C" void kernel_launch(void* const* d_in, const int* in_sizes, int n_in,
                              void* d_out, int out_size, void* d_ws, size_t ws_size,
                              hipStream_t stream) {
    const float* x    = (const float*)d_in[0];
    const float* mask = (const float*)d_in[1];
    const float* wq   = (const float*)d_in[2];
    const float* bq   = (const float*)d_in[3];
    const float* wk   = (const float*)d_in[4];
    const float* bk   = (const float*)d_in[5];
    const float* wv   = (const float*)d_in[6];
    const float* bv   = (const float*)d_in[7];
    const float* wo   = (const float*)d_in[8];
    const float* bo   = (const float*)d_in[9];

    const size_t nX = (size_t)BSZ * S_LEN * DMODEL;      // 8388608
    const size_t nW = (size_t)DMODEL * DMODEL;           // 1048576

    char* ws = (char*)d_ws;
    size_t off = 0;
    bf16_t* xb     = (bf16_t*)(ws + off); off += nX * 2;
    bf16_t* wqkvT  = (bf16_t*)(ws + off); off += 3 * nW * 2;
    bf16_t* woT    = (bf16_t*)(ws + off); off += nW * 2;
    bf16_t* qbh    = (bf16_t*)(ws + off); off += nX * 2;
    bf16_t* kbh    = (bf16_t*)(ws + off); off += nX * 2;
    bf16_t* vrow   = (bf16_t*)(ws + off); off += nX * 2;
    bf16_t* vtb    = (bf16_t*)(ws + off); off += nX * 2;
    bf16_t* ctx    = (bf16_t*)(ws + off); off += nX * 2;
    if (ws_size < off) return;  // workspace too small: loud failure (output stays zero)

    float* outp  = (float*)d_out;
    float* attnW = outp + nX;  // out is B*S*D, then attn weights B*H*S*S

    cvt_x_kernel<<<4096, 256, 0, stream>>>(x, xb, (int)(nX / 4));
    cvt_wT_kernel<<<dim3(16, 16), 256, 0, stream>>>(wq, wqkvT);
    cvt_wT_kernel<<<dim3(16, 16), 256, 0, stream>>>(wk, wqkvT + nW);
    cvt_wT_kernel<<<dim3(16, 16), 256, 0, stream>>>(wv, wqkvT + 2 * nW);
    cvt_wT_kernel<<<dim3(16, 16), 256, 0, stream>>>(wo, woT);

    gemm_bt<0><<<dim3(24, 64), 256, 0, stream>>>(xb, wqkvT, bq, bk, bv,
                                                 qbh, kbh, vrow, nullptr);
    transpose_v<<<dim3(32, 64), 256, 0, stream>>>(vrow, vtb);

    attn_fused<<<512, 256, 0, stream>>>(qbh, kbh, vtb, mask, attnW, ctx);

    gemm_bt<2><<<dim3(8, 64), 256, 0, stream>>>(ctx, woT, bo, nullptr, nullptr,
                                                nullptr, nullptr, nullptr, outp);
}

// Round 12
// 375.853 us; speedup vs baseline: 2.1248x; 1.0181x over previous
//
#include <hip/hip_runtime.h>
#include <hip/hip_bf16.h>

// Problem constants: B=4, S=2048, D=1024, H=16, HD=64
#define S_LEN  2048
#define DMODEL 1024
#define NHEAD  16
#define HDIM   64
#define BSZ    4

// exp2-domain softmax constants
#define C_SCORE  0.18033688f        // 0.125 * log2(e)
#define C_MASK  -1.4426950e9f       // -1e9 * log2(e)

typedef __bf16 bf16_t;
typedef __bf16 bf16x8 __attribute__((ext_vector_type(8)));
typedef __bf16 bf16x4 __attribute__((ext_vector_type(4)));
typedef float  f32x4  __attribute__((ext_vector_type(4)));

typedef __attribute__((address_space(1))) void as1_void;
typedef __attribute__((address_space(3))) void as3_void;

__device__ __forceinline__ f32x4 mfma16(bf16x8 a, bf16x8 b, f32x4 c) {
    return __builtin_amdgcn_mfma_f32_16x16x32_bf16(a, b, c, 0, 0, 0);
}

// ---------------------------------------------------------------------------
// Merged conversion kernel: blocks [0,4096) convert x fp32->bf16 (2 f32x4 per
// thread); blocks [4096, 5120) transpose+convert the 4 weight matrices into
// wT (wq,wk,wv at wT[0..3*nW), wo at wT[3*nW..4*nW)).
__global__ __launch_bounds__(256) void cvt_all(const float* __restrict__ x,
                                               bf16_t* __restrict__ xb,
                                               const float* __restrict__ w0,
                                               const float* __restrict__ w1,
                                               const float* __restrict__ w2,
                                               const float* __restrict__ w3,
                                               bf16_t* __restrict__ wT) {
    __shared__ bf16_t t[64][65];
    const int bid = blockIdx.x;
    if (bid < 4096) {
        const int i0 = bid * 256 + threadIdx.x;
        #pragma unroll
        for (int rep = 0; rep < 2; ++rep) {
            const int i = i0 + rep * 1048576;
            float4 v = ((const float4*)x)[i];
            bf16x4 tv = { (bf16_t)v.x, (bf16_t)v.y, (bf16_t)v.z, (bf16_t)v.w };
            ((bf16x4*)xb)[i] = tv;
        }
        return;
    }
    const int wb = bid - 4096;              // 0..1023
    const int wsel = wb >> 8;               // 0..3
    const float* w = wsel == 0 ? w0 : (wsel == 1 ? w1 : (wsel == 2 ? w2 : w3));
    bf16_t* wTo = wT + (size_t)wsel * DMODEL * DMODEL;
    const int rb = wb & 255;
    const int bx = (rb & 15) * 64, by = (rb >> 4) * 64;
    const int tx = threadIdx.x & 63, ty = threadIdx.x >> 6;
    #pragma unroll
    for (int rr = 0; rr < 64; rr += 4)
        t[tx][rr + ty] = (bf16_t)w[(size_t)(bx + rr + ty) * DMODEL + by + tx];
    __syncthreads();
    #pragma unroll
    for (int rr = 0; rr < 64; rr += 4)
        wTo[(size_t)(by + rr + ty) * DMODEL + bx + tx] = t[rr + ty][tx];
}

// ---------------------------------------------------------------------------
// GEMM: C = A(Mx1024) * Bt(Nx1024)^T + bias. 128x128 tile, 4 waves (2x2).
// MODE 0: fused QKV (N=3072): Q,K bf16 (B,H,S,HD) row-major; V written
//         TRANSPOSED (B,H,HD,S) directly via an LDS round-trip epilogue
//         (replaces the separate transpose_v kernel).
// MODE 2: out-projection (N=1024): fp32 (B,S,D).
template <int MODE>
__global__ __launch_bounds__(256) void gemm_bt(const bf16_t* __restrict__ A,
                                               const bf16_t* __restrict__ Bt,
                                               const float* __restrict__ b0,
                                               const float* __restrict__ b1,
                                               const float* __restrict__ b2,
                                               bf16_t* __restrict__ o0,
                                               bf16_t* __restrict__ o1,
                                               bf16_t* __restrict__ o2,
                                               float* __restrict__ of) {
    constexpr int GK = 1024;
    // As at [0,4096), Bs at [4096,8192); V^T epilogue reuses all 8704 elems
    // as vt[64][136] (17408 B; stride 272 B keeps b128 reads 16B-aligned).
    __shared__ __attribute__((aligned(16))) bf16_t smem_ab[8704];
    bf16_t* As = smem_ab;
    bf16_t* Bs = smem_ab + 4096;

    const int tid  = threadIdx.x;
    const int wave = tid >> 6, lane = tid & 63;
    const int col16 = lane & 15, g = lane >> 4;
    const int wr = wave >> 1, wc = wave & 1;
    const int bn0 = blockIdx.x * 128, bm0 = blockIdx.y * 128;

    const int r4 = tid >> 2;
    const int c8 = (tid & 3) * 8;

    f32x4 acc[4][4] = {};

    for (int k0 = 0; k0 < GK; k0 += 32) {
        __syncthreads();
        #pragma unroll
        for (int i = 0; i < 2; ++i) {
            __builtin_amdgcn_global_load_lds(
                (const as1_void*)(A + (size_t)(bm0 + i * 64 + r4) * GK + k0 + c8),
                (as3_void*)(As + (i * 64 + wave * 16) * 32), 16, 0, 0);
            __builtin_amdgcn_global_load_lds(
                (const as1_void*)(Bt + (size_t)(bn0 + i * 64 + r4) * GK + k0 + c8),
                (as3_void*)(Bs + (i * 64 + wave * 16) * 32), 16, 0, 0);
        }
        __syncthreads();

        bf16x8 af[4], bfr[4];
        #pragma unroll
        for (int i = 0; i < 4; ++i) {
            af[i]  = *(const bf16x8*)(As + (wr * 64 + i * 16 + col16) * 32 + g * 8);
            bfr[i] = *(const bf16x8*)(Bs + (wc * 64 + i * 16 + col16) * 32 + g * 8);
        }
        #pragma unroll
        for (int mi = 0; mi < 4; ++mi)
            #pragma unroll
            for (int ni = 0; ni < 4; ++ni)
                acc[mi][ni] = mfma16(af[mi], bfr[ni], acc[mi][ni]);
    }

    if (MODE == 0 && (bn0 >> 10) == 2) {
        // ---- V path: write V^T (B,H,HD,S) via LDS transpose ----
        const int n1base = bn0 - 2048;            // 0 or 896.. (multiple of 128)
        const int brow = bm0 >> 11;               // batch
        const int s0 = bm0 & 2047;                // s base
        __syncthreads();                          // K-loop LDS reads done
        #pragma unroll
        for (int p = 0; p < 2; ++p) {
            if (p) __syncthreads();               // pass-0 reads done before rewrite
            if (wc == p) {
                #pragma unroll
                for (int ni = 0; ni < 4; ++ni) {
                    const float bv = b2[n1base + p * 64 + ni * 16 + col16];
                    #pragma unroll
                    for (int mi = 0; mi < 4; ++mi) {
                        bf16x4 pv;
                        #pragma unroll
                        for (int r = 0; r < 4; ++r) pv[r] = (bf16_t)(acc[mi][ni][r] + bv);
                        *(bf16x4*)&smem_ab[(ni * 16 + col16) * 136 + wr * 64 + mi * 16 + g * 4] = pv;
                    }
                }
            }
            __syncthreads();
            const int h2 = (n1base + p * 64) >> 6;
            bf16_t* vout = o2 + (((size_t)brow * NHEAD + h2) * HDIM) * S_LEN + s0;
            #pragma unroll
            for (int j = 0; j < 4; ++j) {
                const int unit = j * 256 + tid;   // 0..1023
                const int row = unit >> 4;        // hd 0..63
                const int cu = (unit & 15) * 8;   // s offset
                bf16x8 v = *(const bf16x8*)&smem_ab[row * 136 + cu];
                *(bf16x8*)(vout + (size_t)row * S_LEN + cu) = v;
            }
        }
        return;
    }

    #pragma unroll
    for (int ni = 0; ni < 4; ++ni) {
        const int gn = bn0 + wc * 64 + ni * 16 + col16;
        if (MODE == 0) {
            const int proj = bn0 >> 10;           // 0 or 1 here (V handled above)
            const float* bias = proj == 0 ? b0 : b1;
            bf16_t* outp      = proj == 0 ? o0 : o1;
            const int n1 = gn & 1023, h = n1 >> 6, hd = n1 & 63;
            const float bv = bias[n1];
            #pragma unroll
            for (int mi = 0; mi < 4; ++mi)
                #pragma unroll
                for (int r = 0; r < 4; ++r) {
                    const int gm = bm0 + wr * 64 + mi * 16 + g * 4 + r;
                    const int b = gm >> 11, s = gm & 2047;
                    outp[(((size_t)b * NHEAD + h) * S_LEN + s) * HDIM + hd] =
                        (bf16_t)(acc[mi][ni][r] + bv);
                }
        } else {
            const float bv = b0[gn];
            #pragma unroll
            for (int mi = 0; mi < 4; ++mi)
                #pragma unroll
                for (int r = 0; r < 4; ++r) {
                    const int gm = bm0 + wr * 64 + mi * 16 + g * 4 + r;
                    of[(size_t)gm * DMODEL + gn] = acc[mi][ni][r] + bv;
                }
        }
    }
}

// ---------------------------------------------------------------------------
// Fused attention v12: v11 2-tile phase pipeline + 128-row loop-A chunks.
// Carved shared memory (72 KB -> 2 blocks/CU):
//   [0,32K):  loop A: KsA[2][128][64]   |  loops B/C: Ks[2][64][64]+Vs[2][64][64]
//   [32K,64K): Pl[4][32][64] fp32 (store round-trip, B/C only)
//   [64K,72K): Ml[2048] fp32 (mask * C_MASK, loaded once)
// Loop A: l(tile0), 16 iterations of 128 k-rows (half the barriers of v11).
// Loop B: one K+V stage stream serves tile0's store sweep AND tile1's l.
// Loop C: tile1 store sweep. Counted vmcnt(8) keeps stores in flight.
__global__ __launch_bounds__(256, 2) void attn_fused(const bf16_t* __restrict__ Q,
                                                     const bf16_t* __restrict__ K,
                                                     const bf16_t* __restrict__ Vt,
                                                     const float* __restrict__ mask,
                                                     float* __restrict__ attnW,
                                                     bf16_t* __restrict__ ctx) {
    __shared__ __attribute__((aligned(16))) char smem[73728];
    bf16_t (*KsA)[128][64] = (bf16_t(*)[128][64])smem;            // loop A view
    bf16_t (*Ks)[64][64]   = (bf16_t(*)[64][64])smem;             // B/C view
    bf16_t (*Vs)[64][64]   = (bf16_t(*)[64][64])(smem + 16384);
    float  (*Pl)[32][64]   = (float(*)[32][64])(smem + 32768);
    float*  Ml             = (float*)(smem + 65536);

    const int tid = threadIdx.x, wave = tid >> 6, lane = tid & 63;
    const int col16 = lane & 15, g = lane >> 4;
    const int r7 = col16 & 7;

    // bijective XCD swizzle (512 blocks, 512 % 8 == 0): 8 heads per XCD
    const int lin = blockIdx.x;
    const int logical = (lin & 7) * 64 + (lin >> 3);
    const int bh = logical >> 3, pp = logical & 7;
    const int b = bh >> 4, h = bh & 15;
    const int qA = pp * 256 + wave * 32;
    const int qB = pp * 256 + 128 + wave * 32;

    const bf16_t* Qb = Q + (size_t)bh * S_LEN * HDIM;
    const bf16_t* Kb = K + (size_t)bh * S_LEN * HDIM;
    const bf16_t* Vb = Vt + (size_t)bh * HDIM * S_LEN;
    const float* mp = mask + (size_t)b * S_LEN;

    // mask * C_MASK -> LDS once
    #pragma unroll
    for (int i = 0; i < 2; ++i) {
        const int idx = i * 256 + tid;
        f32x4 v = ((const f32x4*)mp)[idx];
        #pragma unroll
        for (int r = 0; r < 4; ++r) v[r] *= C_MASK;
        *(f32x4*)(&Ml[idx * 4]) = v;
    }

    // staging lane constants: linear LDS dest, pre-swizzled global source
    const int srow  = lane >> 3;
    const int sunit = (lane & 7) ^ srow;

    auto stageA = [&](int buf, int it) {       // 128 k-rows per buffer
        const int kk0 = it << 7;
        #pragma unroll
        for (int i2 = 0; i2 < 4; ++i2) {
            const int i = wave * 4 + i2;       // chunk 0..15 (8 rows each)
            __builtin_amdgcn_global_load_lds(
                (const as1_void*)(Kb + (size_t)(kk0 + i * 8 + srow) * HDIM + sunit * 8),
                (as3_void*)(&KsA[buf][i * 8][0]), 16, 0, 0);
        }
    };
    auto stageK = [&](int buf, int it) {
        const int kk0 = it << 6;
        #pragma unroll
        for (int i2 = 0; i2 < 2; ++i2) {
            const int i = wave * 2 + i2;
            __builtin_amdgcn_global_load_lds(
                (const as1_void*)(Kb + (size_t)(kk0 + i * 8 + srow) * HDIM + sunit * 8),
                (as3_void*)(&Ks[buf][i * 8][0]), 16, 0, 0);
        }
    };
    auto stageV = [&](int buf, int it) {
        const int kk0 = it << 6;
        #pragma unroll
        for (int i2 = 0; i2 < 2; ++i2) {
            const int i = wave * 2 + i2;
            __builtin_amdgcn_global_load_lds(
                (const as1_void*)(Vb + (size_t)(i * 8 + srow) * S_LEN + kk0 + sunit * 8),
                (as3_void*)(&Vs[buf][i * 8][0]), 16, 0, 0);
        }
    };
    auto kfrag = [&](int buf, int nj, int kh) {
        return *(const bf16x8*)(&Ks[buf][nj * 16 + col16][(((kh * 4 + g) ^ r7) * 8)]);
    };
    auto vfrag = [&](int buf, int nd, int kh) {
        return *(const bf16x8*)(&Vs[buf][nd * 16 + col16][(((kh * 4 + g) ^ r7) * 8)]);
    };

    // Q B-frags for both tiles, both 16-row halves
    bf16x8 qa0[2][2], qa1[2][2];
    #pragma unroll
    for (int hh = 0; hh < 2; ++hh)
        #pragma unroll
        for (int kh = 0; kh < 2; ++kh) {
            qa0[hh][kh] = *(const bf16x8*)(Qb + (size_t)(qA + hh * 16 + col16) * HDIM +
                                           kh * 32 + g * 8);
            qa1[hh][kh] = *(const bf16x8*)(Qb + (size_t)(qB + hh * 16 + col16) * HDIM +
                                           kh * 32 + g * 8);
        }

    // ================= loop A: l(tile0), 128-row chunks =================
    f32x4 lacc[2] = {};
    stageA(0, 0);
    __syncthreads();   // Ml fill + stage(0) ready

    for (int it = 0; it < 16; ++it) {
        const int kk0 = it << 7, cur = it & 1;
        if (it < 15) stageA(cur ^ 1, it + 1);
        #pragma unroll
        for (int nj = 0; nj < 8; ++nj) {
            const f32x4 mvr = *(const f32x4*)(&Ml[kk0 + nj * 16 + g * 4]);
            const bf16x8 kf0 = *(const bf16x8*)(&KsA[cur][nj * 16 + col16][((g ^ r7) * 8)]);
            const bf16x8 kf1 = *(const bf16x8*)(&KsA[cur][nj * 16 + col16][(((4 + g) ^ r7) * 8)]);
            f32x4 t0 = {0.f, 0.f, 0.f, 0.f}, t1 = {0.f, 0.f, 0.f, 0.f};
            t0 = mfma16(kf0, qa0[0][0], t0);
            t0 = mfma16(kf1, qa0[0][1], t0);
            t1 = mfma16(kf0, qa0[1][0], t1);
            t1 = mfma16(kf1, qa0[1][1], t1);
            #pragma unroll
            for (int r = 0; r < 4; ++r) {
                lacc[0][r] += exp2f(fmaf(t0[r], C_SCORE, mvr[r]));
                lacc[1][r] += exp2f(fmaf(t1[r], C_SCORE, mvr[r]));
            }
        }
        asm volatile("s_waitcnt vmcnt(0)" ::: "memory");
        __builtin_amdgcn_sched_barrier(0);
        __builtin_amdgcn_s_barrier();
    }

    float crow0[2];
    #pragma unroll
    for (int hh = 0; hh < 2; ++hh) {
        float lr = (lacc[hh][0] + lacc[hh][1]) + (lacc[hh][2] + lacc[hh][3]);
        lr += __shfl_xor(lr, 16);
        lr += __shfl_xor(lr, 32);
        crow0[hh] = -__log2f(lr);
        lacc[hh] = (f32x4){0.f, 0.f, 0.f, 0.f};   // reuse for tile1
    }

    // ================= loop B: store(tile0) + l(tile1) =================
    f32x4 o[2][4] = {};
    float* awbase = attnW + ((size_t)bh * S_LEN + qA) * S_LEN;

    stageK(0, 0);
    stageV(0, 0);
    asm volatile("s_waitcnt vmcnt(0)" ::: "memory");
    __builtin_amdgcn_sched_barrier(0);
    __builtin_amdgcn_s_barrier();

    for (int it = 0; it < 32; ++it) {
        const int kk0 = it << 6, cur = it & 1;
        if (it < 31) { stageK(cur ^ 1, it + 1); stageV(cur ^ 1, it + 1); }
        f32x4 mvr[4];
        #pragma unroll
        for (int nj = 0; nj < 4; ++nj)
            mvr[nj] = *(const f32x4*)(&Ml[kk0 + nj * 16 + g * 4]);

        #pragma unroll
        for (int nj = 0; nj < 4; ++nj) {
            const bf16x8 kf0 = kfrag(cur, nj, 0);
            const bf16x8 kf1 = kfrag(cur, nj, 1);
            f32x4 s0 = {0.f, 0.f, 0.f, 0.f}, s1 = {0.f, 0.f, 0.f, 0.f};
            f32x4 u0 = {0.f, 0.f, 0.f, 0.f}, u1 = {0.f, 0.f, 0.f, 0.f};
            s0 = mfma16(kf0, qa0[0][0], s0);
            s0 = mfma16(kf1, qa0[0][1], s0);
            s1 = mfma16(kf0, qa0[1][0], s1);
            s1 = mfma16(kf1, qa0[1][1], s1);
            u0 = mfma16(kf0, qa1[0][0], u0);
            u0 = mfma16(kf1, qa1[0][1], u0);
            u1 = mfma16(kf0, qa1[1][0], u1);
            u1 = mfma16(kf1, qa1[1][1], u1);
            f32x4 pn0, pn1;
            #pragma unroll
            for (int r = 0; r < 4; ++r) {
                const float mm = mvr[nj][r];
                pn0[r] = exp2f(fmaf(s0[r], C_SCORE, mm + crow0[0]));
                pn1[r] = exp2f(fmaf(s1[r], C_SCORE, mm + crow0[1]));
                lacc[0][r] += exp2f(fmaf(u0[r], C_SCORE, mm));
                lacc[1][r] += exp2f(fmaf(u1[r], C_SCORE, mm));
            }
            const int pw = ((nj * 4 + g) ^ r7) * 4;
            *(f32x4*)(&Pl[wave][col16][pw])      = pn0;
            *(f32x4*)(&Pl[wave][16 + col16][pw]) = pn1;
        }

        // coalesced nt-stores (tile0): 8 instrs x 8 full 128B lines
        #pragma unroll
        for (int j = 0; j < 8; ++j) {
            const int row = j * 4 + (lane >> 4);
            const int u = lane & 15;
            const f32x4 v = *(const f32x4*)(&Pl[wave][row][((u ^ (row & 7)) * 4)]);
            __builtin_nontemporal_store(v, (f32x4*)(awbase + (size_t)row * S_LEN + kk0 + u * 4));
        }

        // PV (tile0) from LDS
        #pragma unroll
        for (int hh = 0; hh < 2; ++hh)
            #pragma unroll
            for (int kh = 0; kh < 2; ++kh) {
                const int u0i = kh * 8 + g * 2;
                const f32x4 a0 = *(const f32x4*)(&Pl[wave][hh * 16 + col16][((u0i ^ r7) * 4)]);
                const f32x4 a1 = *(const f32x4*)(&Pl[wave][hh * 16 + col16][(((u0i + 1) ^ r7) * 4)]);
                bf16x8 pa;
                #pragma unroll
                for (int j = 0; j < 4; ++j) {
                    pa[j]     = (bf16_t)a0[j];
                    pa[4 + j] = (bf16_t)a1[j];
                }
                #pragma unroll
                for (int nd = 0; nd < 4; ++nd)
                    o[hh][nd] = mfma16(vfrag(cur, nd, kh), pa, o[hh][nd]);
            }

        asm volatile("s_waitcnt vmcnt(8)" ::: "memory");
        __builtin_amdgcn_sched_barrier(0);
        __builtin_amdgcn_s_barrier();
    }

    float crow1[2];
    #pragma unroll
    for (int hh = 0; hh < 2; ++hh) {
        float lr = (lacc[hh][0] + lacc[hh][1]) + (lacc[hh][2] + lacc[hh][3]);
        lr += __shfl_xor(lr, 16);
        lr += __shfl_xor(lr, 32);
        crow1[hh] = -__log2f(lr);
    }

    // ctx (tile0)
    #pragma unroll
    for (int hh = 0; hh < 2; ++hh) {
        bf16_t* cp = ctx + ((size_t)b * S_LEN + qA + hh * 16 + col16) * DMODEL + h * HDIM;
        #pragma unroll
        for (int nd = 0; nd < 4; ++nd) {
            bf16x4 cv;
            #pragma unroll
            for (int r = 0; r < 4; ++r) cv[r] = (bf16_t)o[hh][nd][r];
            *(bf16x4*)(cp + nd * 16 + g * 4) = cv;
        }
        o[hh][0] = o[hh][1] = o[hh][2] = o[hh][3] = (f32x4){0.f, 0.f, 0.f, 0.f};
    }

    // ================= loop C: store(tile1) =================
    awbase = attnW + ((size_t)bh * S_LEN + qB) * S_LEN;

    stageK(0, 0);
    stageV(0, 0);
    asm volatile("s_waitcnt vmcnt(0)" ::: "memory");
    __builtin_amdgcn_sched_barrier(0);
    __builtin_amdgcn_s_barrier();

    for (int it = 0; it < 32; ++it) {
        const int kk0 = it << 6, cur = it & 1;
        if (it < 31) { stageK(cur ^ 1, it + 1); stageV(cur ^ 1, it + 1); }
        f32x4 mvr[4];
        #pragma unroll
        for (int nj = 0; nj < 4; ++nj)
            mvr[nj] = *(const f32x4*)(&Ml[kk0 + nj * 16 + g * 4]);

        #pragma unroll
        for (int nj = 0; nj < 4; ++nj) {
            const bf16x8 kf0 = kfrag(cur, nj, 0);
            const bf16x8 kf1 = kfrag(cur, nj, 1);
            f32x4 t0 = {0.f, 0.f, 0.f, 0.f}, t1 = {0.f, 0.f, 0.f, 0.f};
            t0 = mfma16(kf0, qa1[0][0], t0);
            t0 = mfma16(kf1, qa1[0][1], t0);
            t1 = mfma16(kf0, qa1[1][0], t1);
            t1 = mfma16(kf1, qa1[1][1], t1);
            f32x4 pn0, pn1;
            #pragma unroll
            for (int r = 0; r < 4; ++r) {
                const float mm = mvr[nj][r];
                pn0[r] = exp2f(fmaf(t0[r], C_SCORE, mm + crow1[0]));
                pn1[r] = exp2f(fmaf(t1[r], C_SCORE, mm + crow1[1]));
            }
            const int pw = ((nj * 4 + g) ^ r7) * 4;
            *(f32x4*)(&Pl[wave][col16][pw])      = pn0;
            *(f32x4*)(&Pl[wave][16 + col16][pw]) = pn1;
        }

        #pragma unroll
        for (int j = 0; j < 8; ++j) {
            const int row = j * 4 + (lane >> 4);
            const int u = lane & 15;
            const f32x4 v = *(const f32x4*)(&Pl[wave][row][((u ^ (row & 7)) * 4)]);
            __builtin_nontemporal_store(v, (f32x4*)(awbase + (size_t)row * S_LEN + kk0 + u * 4));
        }

        #pragma unroll
        for (int hh = 0; hh < 2; ++hh)
            #pragma unroll
            for (int kh = 0; kh < 2; ++kh) {
                const int u0i = kh * 8 + g * 2;
                const f32x4 a0 = *(const f32x4*)(&Pl[wave][hh * 16 + col16][((u0i ^ r7) * 4)]);
                const f32x4 a1 = *(const f32x4*)(&Pl[wave][hh * 16 + col16][(((u0i + 1) ^ r7) * 4)]);
                bf16x8 pa;
                #pragma unroll
                for (int j = 0; j < 4; ++j) {
                    pa[j]     = (bf16_t)a0[j];
                    pa[4 + j] = (bf16_t)a1[j];
                }
                #pragma unroll
                for (int nd = 0; nd < 4; ++nd)
                    o[hh][nd] = mfma16(vfrag(cur, nd, kh), pa, o[hh][nd]);
            }

        asm volatile("s_waitcnt vmcnt(8)" ::: "memory");
        __builtin_amdgcn_sched_barrier(0);
        __builtin_amdgcn_s_barrier();
    }

    // ctx (tile1)
    #pragma unroll
    for (int hh = 0; hh < 2; ++hh) {
        bf16_t* cp = ctx + ((size_t)b * S_LEN + qB + hh * 16 + col16) * DMODEL + h * HDIM;
        #pragma unroll
        for (int nd = 0; nd < 4; ++nd) {
            bf16x4 cv;
            #pragma unroll
            for (int r = 0; r < 4; ++r) cv[r] = (bf16_t)o[hh][nd][r];
            *(bf16x4*)(cp + nd * 16 + g * 4) = cv;
        }
    }
}

// ---------------------------------------------------------------------------
extern "C" void kernel_launch(void* const* d_in, const int* in_sizes, int n_in,
                              void* d_out, int out_size, void* d_ws, size_t ws_size,
                              hipStream_t stream) {
    const float* x    = (const float*)d_in[0];
    const float* mask = (const float*)d_in[1];
    const float* wq   = (const float*)d_in[2];
    const float* bq   = (const float*)d_in[3];
    const float* wk   = (const float*)d_in[4];
    const float* bk   = (const float*)d_in[5];
    const float* wv   = (const float*)d_in[6];
    const float* bv   = (const float*)d_in[7];
    const float* wo   = (const float*)d_in[8];
    const float* bo   = (const float*)d_in[9];

    const size_t nX = (size_t)BSZ * S_LEN * DMODEL;      // 8388608
    const size_t nW = (size_t)DMODEL * DMODEL;           // 1048576

    char* ws = (char*)d_ws;
    size_t off = 0;
    bf16_t* xb     = (bf16_t*)(ws + off); off += nX * 2;
    bf16_t* wqkvT  = (bf16_t*)(ws + off); off += 3 * nW * 2;
    bf16_t* woT    = (bf16_t*)(ws + off); off += nW * 2;   // contiguous after wqkvT
    bf16_t* qbh    = (bf16_t*)(ws + off); off += nX * 2;
    bf16_t* kbh    = (bf16_t*)(ws + off); off += nX * 2;
    bf16_t* vtb    = (bf16_t*)(ws + off); off += nX * 2;
    bf16_t* ctx    = (bf16_t*)(ws + off); off += nX * 2;
    if (ws_size < off) return;  // workspace too small: loud failure (output stays zero)

    float* outp  = (float*)d_out;
    float* attnW = outp + nX;  // out is B*S*D, then attn weights B*H*S*S

    cvt_all<<<5120, 256, 0, stream>>>(x, xb, wq, wk, wv, wo, wqkvT);

    gemm_bt<0><<<dim3(24, 64), 256, 0, stream>>>(xb, wqkvT, bq, bk, bv,
                                                 qbh, kbh, vtb, nullptr);

    attn_fused<<<512, 256, 0, stream>>>(qbh, kbh, vtb, mask, attnW, ctx);

    gemm_bt<2><<<dim3(8, 64), 256, 0, stream>>>(ctx, woT, bo, nullptr, nullptr,
                                                nullptr, nullptr, nullptr, outp);
}